// Round 5
// baseline (4305.612 us; speedup 1.0000x reference)
//
#include <hip/hip_runtime.h>
#include <math.h>

#define DIM    768
#define BATCH  1024
#define NANS   128000
#define NTILES 500              // 256-answer tiles
#define CAND_PER_ROW (NTILES*10)
#define NWORDS 4000             // mask bit-words per batch row (128000/32)

typedef short  bf16x8 __attribute__((ext_vector_type(8)));
typedef float  f32x4  __attribute__((ext_vector_type(4)));

__device__ __forceinline__ short f2bf(float x)
{
    unsigned u = __builtin_bit_cast(unsigned, x);
    u += 0x7fffu + ((u >> 16) & 1u);          // RNE (no NaN inputs here)
    return (short)(u >> 16);
}

// sorted-descending top-10 insertion (branchless swap chain, static indices)
__device__ __forceinline__ void ins10(float (&s)[10], int (&ix)[10], float v, int vi)
{
    if (v > s[9] || (v == s[9] && vi < ix[9])) {
        s[9] = v; ix[9] = vi;
        #pragma unroll
        for (int q = 9; q > 0; --q) {
            bool sw = (s[q] > s[q-1]) || (s[q] == s[q-1] && ix[q] < ix[q-1]);
            float ts = s[q-1]; int ti = ix[q-1];
            s[q-1] = sw ? s[q] : s[q-1]; ix[q-1] = sw ? ix[q] : ix[q-1];
            s[q]   = sw ? ts   : s[q];   ix[q]   = sw ? ti   : ix[q];
        }
    }
}

// ---------------------------------------------------------------------------
// Upstream GEMM: C[M,N] = A[M,K] @ W[N,K]^T + bias   (fp32)
// ---------------------------------------------------------------------------
__global__ __launch_bounds__(256, 2) void gemm_bias_k(
    const float* __restrict__ A, int lda,
    const float* __restrict__ W,
    const float* __restrict__ bias,
    float* __restrict__ C, int ldc, int K)
{
    __shared__ float as[32][68];
    __shared__ float bs[32][68];
    int m0 = blockIdx.x * 64, n0 = blockIdx.y * 64;
    int tid = threadIdx.x;
    int tm = tid & 15, tn = tid >> 4;
    int sr = tid >> 3, skq = tid & 7;
    float acc[4][4] = {};
    for (int k0 = 0; k0 < K; k0 += 32) {
        __syncthreads();
        #pragma unroll
        for (int p = 0; p < 2; ++p) {
            int r = sr + 32 * p;
            float4 av = *(const float4*)&A[(size_t)(m0 + r) * lda + k0 + skq * 4];
            as[skq*4+0][r] = av.x; as[skq*4+1][r] = av.y;
            as[skq*4+2][r] = av.z; as[skq*4+3][r] = av.w;
            float4 wv = *(const float4*)&W[(size_t)(n0 + r) * K + k0 + skq * 4];
            bs[skq*4+0][r] = wv.x; bs[skq*4+1][r] = wv.y;
            bs[skq*4+2][r] = wv.z; bs[skq*4+3][r] = wv.w;
        }
        __syncthreads();
        #pragma unroll 8
        for (int k = 0; k < 32; ++k) {
            float a4[4], b4[4];
            *(float4*)a4 = *(const float4*)&as[k][tm*4];
            *(float4*)b4 = *(const float4*)&bs[k][tn*4];
            #pragma unroll
            for (int i = 0; i < 4; ++i)
                #pragma unroll
                for (int j = 0; j < 4; ++j)
                    acc[i][j] = fmaf(a4[i], b4[j], acc[i][j]);
        }
    }
    float4 bv4 = *(const float4*)&bias[n0 + tn*4];
    #pragma unroll
    for (int i = 0; i < 4; ++i) {
        float4 c4;
        c4.x = acc[i][0] + bv4.x; c4.y = acc[i][1] + bv4.y;
        c4.z = acc[i][2] + bv4.z; c4.w = acc[i][3] + bv4.w;
        *(float4*)&C[(size_t)(m0 + tm*4 + i) * ldc + n0 + tn*4] = c4;
    }
}

// ---------------------------------------------------------------------------
__global__ void copy_visual_k(const float* __restrict__ src, float* __restrict__ dst)
{
    int idx = blockIdx.x * 256 + threadIdx.x;          // float4 index
    const int total = BATCH * (DIM / 4);
    for (; idx < total; idx += 512 * 256) {
        int b = idx / (DIM / 4), c = idx % (DIM / 4);
        ((float4*)dst)[(size_t)b * (1536 / 4) + c] = ((const float4*)src)[idx];
    }
}

// ---------------------------------------------------------------------------
__device__ __forceinline__ float block_sum(float v, float* red)
{
    #pragma unroll
    for (int o = 32; o; o >>= 1) v += __shfl_down(v, o);
    if ((threadIdx.x & 63) == 0) red[threadIdx.x >> 6] = v;
    __syncthreads();
    float r = red[0] + red[1] + red[2] + red[3];
    __syncthreads();
    return r;
}

__global__ __launch_bounds__(256) void ln_gelu_k(float* __restrict__ H,
        const float* __restrict__ g, const float* __restrict__ b)
{
    __shared__ float red[4];
    int row = blockIdx.x, tid = threadIdx.x;
    float* hr = H + (size_t)row * DIM;
    float v0 = hr[tid], v1 = hr[tid + 256], v2 = hr[tid + 512];
    float mu = block_sum(v0 + v1 + v2, red) * (1.0f / 768.0f);
    float d0 = v0 - mu, d1 = v1 - mu, d2 = v2 - mu;
    float var = block_sum(d0*d0 + d1*d1 + d2*d2, red) * (1.0f / 768.0f);
    float rinv = 1.0f / sqrtf(var + 1e-5f);
    #pragma unroll
    for (int q = 0; q < 3; ++q) {
        int d = tid + 256 * q;
        float dd = (q == 0 ? d0 : (q == 1 ? d1 : d2));
        float y = dd * rinv * g[d] + b[d];
        hr[d] = 0.5f * y * (1.0f + erff(y * 0.70710678118654752f));
    }
}

// l2-normalize P in place, also emit bf16 copy
__global__ __launch_bounds__(256) void l2norm_bf_k(float* __restrict__ P,
        short* __restrict__ Pb)
{
    __shared__ float red[4];
    int row = blockIdx.x, tid = threadIdx.x;
    float* pr = P + (size_t)row * DIM;
    short* pb = Pb + (size_t)row * DIM;
    float v0 = pr[tid], v1 = pr[tid + 256], v2 = pr[tid + 512];
    float ss = block_sum(v0*v0 + v1*v1 + v2*v2, red);
    float inv = 1.0f / fmaxf(sqrtf(ss), 1e-12f);
    v0 *= inv; v1 *= inv; v2 *= inv;
    pr[tid] = v0; pr[tid + 256] = v1; pr[tid + 512] = v2;
    pb[tid] = f2bf(v0); pb[tid + 256] = f2bf(v1); pb[tid + 512] = f2bf(v2);
}

// ---------------------------------------------------------------------------
// prep_ans: fp64 row norm -> inv64[row]; write unit-normalized bf16 rows into
// the chunk buffer AB (local row r = global row0+r). One wave per row.
// ---------------------------------------------------------------------------
__global__ __launch_bounds__(256) void prep_ans_k(
    const float* __restrict__ ANS, int row0, int nrows,
    double* __restrict__ inv64, short* __restrict__ AB)
{
    int r = blockIdx.x * 4 + (threadIdx.x >> 6);
    if (r >= nrows) return;
    int row = row0 + r;
    int lane = threadIdx.x & 63;
    const float4* a4 = (const float4*)(ANS + (size_t)row * DIM);
    float4 x0 = a4[lane], x1 = a4[lane + 64], x2 = a4[lane + 128];
    double ss = (double)x0.x*x0.x + (double)x0.y*x0.y + (double)x0.z*x0.z + (double)x0.w*x0.w
              + (double)x1.x*x1.x + (double)x1.y*x1.y + (double)x1.z*x1.z + (double)x1.w*x1.w
              + (double)x2.x*x2.x + (double)x2.y*x2.y + (double)x2.z*x2.z + (double)x2.w*x2.w;
    #pragma unroll
    for (int o = 32; o; o >>= 1) ss += __shfl_xor(ss, o);
    double inv = 1.0 / fmax(sqrt(ss), 1e-12);
    if (lane == 0) inv64[row] = inv;
    float invf = (float)inv;
    short* ob = AB + (size_t)r * DIM;
    ushort4 o0, o1, o2;
    o0.x = (unsigned short)f2bf(x0.x*invf); o0.y = (unsigned short)f2bf(x0.y*invf);
    o0.z = (unsigned short)f2bf(x0.z*invf); o0.w = (unsigned short)f2bf(x0.w*invf);
    o1.x = (unsigned short)f2bf(x1.x*invf); o1.y = (unsigned short)f2bf(x1.y*invf);
    o1.z = (unsigned short)f2bf(x1.z*invf); o1.w = (unsigned short)f2bf(x1.w*invf);
    o2.x = (unsigned short)f2bf(x2.x*invf); o2.y = (unsigned short)f2bf(x2.y*invf);
    o2.z = (unsigned short)f2bf(x2.z*invf); o2.w = (unsigned short)f2bf(x2.w*invf);
    *(ushort4*)&ob[lane * 4]           = o0;
    *(ushort4*)&ob[(lane + 64) * 4]    = o1;
    *(ushort4*)&ob[(lane + 128) * 4]   = o2;
}

// ---------------------------------------------------------------------------
// prep_mask: float mask [1024][128000] -> bits [1024][4000]
// ---------------------------------------------------------------------------
__global__ __launch_bounds__(256) void prep_mask_k(
    const float* __restrict__ mask, unsigned* __restrict__ bits)
{
    int row = blockIdx.x;
    const float* mr = mask + (size_t)row * NANS;
    unsigned* br = bits + (size_t)row * NWORDS;
    for (int w = threadIdx.x; w < NWORDS; w += 256) {
        const float4* p = (const float4*)(mr + w * 32);
        unsigned b = 0;
        #pragma unroll
        for (int q = 0; q < 8; ++q) {
            float4 v = p[q];
            b |= ((unsigned)(v.x != 0.f)) << (q*4+0);
            b |= ((unsigned)(v.y != 0.f)) << (q*4+1);
            b |= ((unsigned)(v.z != 0.f)) << (q*4+2);
            b |= ((unsigned)(v.w != 0.f)) << (q*4+3);
        }
        br[w] = b;
    }
}

// ---------------------------------------------------------------------------
// Big MFMA kernel v3: 256 answers x 64 batch per block, 512 thr (8 waves,
// each owning a 32x64 sub-tile -> acc[2][4] = 32 VGPRs). BK=64, reg staging,
// bitmask epilogue, per-(row, 256-answer-tile) top-10 shortlist.
// ---------------------------------------------------------------------------
__global__ __launch_bounds__(512, 4) void big3_k(
    const short* __restrict__ Pb,       // [1024][768] unit-norm bf16
    const short* __restrict__ AB,       // chunk [catiles*256][768] unit-norm bf16
    const unsigned* __restrict__ bits,  // [1024][4000]
    float* __restrict__ cs, int* __restrict__ ci,
    int atile0, int catiles)
{
    __shared__ __align__(16) char smem[48128];
    short* a_sh = (short*)smem;                 // [256][72] = 36864 B
    short* b_sh = (short*)(smem + 36864);       // [64][72]  =  9216 B
    unsigned* mb = (unsigned*)(smem + 46080);   // [64][8]   =  2048 B
    float* scl = (float*)smem;                  // reuse: [64 ans][68] = 17408 B
    float* ms  = (float*)smem;                  // reuse: [64][80] f32
    int*   mi  = (int*)(smem + 20480);          // reuse: [64][80] i32

    // XCD swizzle: blocks with equal bid%8 (one XCD) share an answer tile
    int bid = blockIdx.x;
    int cpx = catiles * 2;                      // blocks per XCD
    int v = (bid & 7) * cpx + (bid >> 3);       // bijective (nwg%8==0)
    int atile = v >> 4, btile = v & 15;
    int gatile = atile0 + atile;
    int a0l = atile * 256, a0g = gatile * 256, b0 = btile * 64;

    int t = threadIdx.x;
    int lane = t & 63, wid = t >> 6;
    int lr = lane & 15, lg = lane >> 4;

    // stage mask bits: 64 rows x 8 words = 512, one per thread
    mb[t] = bits[(size_t)(b0 + (t >> 3)) * NWORDS + gatile * 8 + (t & 7)];

    // staging: thread owns (srow 0..63, sseg); A rows srow+64p p=0..3, B p=0
    int srow = t >> 3, sseg = (t & 7) * 8;
    const short* gA = AB + (size_t)(a0l + srow) * DIM + sseg;
    const short* gB = Pb + (size_t)(b0  + srow) * DIM + sseg;
    short* wA = a_sh + srow * 72 + sseg;
    short* wB = b_sh + srow * 72 + sseg;

    f32x4 acc[2][4];
    #pragma unroll
    for (int i = 0; i < 2; ++i)
        #pragma unroll
        for (int j = 0; j < 4; ++j)
            acc[i][j] = (f32x4){0.f, 0.f, 0.f, 0.f};

    bf16x8 rA0 = *(const bf16x8*)(gA);
    bf16x8 rA1 = *(const bf16x8*)(gA + 64 * DIM);
    bf16x8 rA2 = *(const bf16x8*)(gA + 128 * DIM);
    bf16x8 rA3 = *(const bf16x8*)(gA + 192 * DIM);
    bf16x8 rB0 = *(const bf16x8*)(gB);

    for (int kt = 0; kt < 12; ++kt) {
        __syncthreads();                        // prev MFMA reads done
        *(bf16x8*)(wA)            = rA0;
        *(bf16x8*)(wA +  64 * 72) = rA1;
        *(bf16x8*)(wA + 128 * 72) = rA2;
        *(bf16x8*)(wA + 192 * 72) = rA3;
        *(bf16x8*)(wB)            = rB0;
        if (kt < 11) {                          // issue next K-tile early
            int ko = (kt + 1) * 64;
            rA0 = *(const bf16x8*)(gA + ko);
            rA1 = *(const bf16x8*)(gA + 64 * DIM + ko);
            rA2 = *(const bf16x8*)(gA + 128 * DIM + ko);
            rA3 = *(const bf16x8*)(gA + 192 * DIM + ko);
            rB0 = *(const bf16x8*)(gB + ko);
        }
        __syncthreads();                        // writes visible
        #pragma unroll
        for (int h = 0; h < 2; ++h) {
            bf16x8 af[2], bg[4];
            #pragma unroll
            for (int mt = 0; mt < 2; ++mt)
                af[mt] = *(const bf16x8*)(a_sh + (wid*32 + mt*16 + lr) * 72 + h*32 + lg*8);
            #pragma unroll
            for (int nt = 0; nt < 4; ++nt)
                bg[nt] = *(const bf16x8*)(b_sh + (nt*16 + lr) * 72 + h*32 + lg*8);
            #pragma unroll
            for (int mt = 0; mt < 2; ++mt)
                #pragma unroll
                for (int nt = 0; nt < 4; ++nt)
                    acc[mt][nt] = __builtin_amdgcn_mfma_f32_16x16x32_bf16(
                        af[mt], bg[nt], acc[mt][nt], 0, 0, 0);
        }
    }

    // ---- epilogue: bitmask + per-column top-10 over the 256-answer tile ----
    float s10[10]; int i10[10];
    #pragma unroll
    for (int q = 0; q < 10; ++q) { s10[q] = -INFINITY; i10[q] = 0x7fffffff; }
    int col = t & 63, qt = t >> 6;              // 8 groups x 8 answers each

    for (int c = 0; c < 4; ++c) {               // 64-answer chunks
        __syncthreads();
        if ((wid >> 1) == c) {                  // waves 2c, 2c+1 dump
            int sub = wid & 1;
            #pragma unroll
            for (int nt = 0; nt < 4; ++nt) {
                int lcol = nt * 16 + lr;
                #pragma unroll
                for (int mt = 0; mt < 2; ++mt) {
                    int lrow = sub * 32 + mt * 16 + lg * 4;
                    scl[(lrow + 0) * 68 + lcol] = acc[mt][nt][0];
                    scl[(lrow + 1) * 68 + lcol] = acc[mt][nt][1];
                    scl[(lrow + 2) * 68 + lcol] = acc[mt][nt][2];
                    scl[(lrow + 3) * 68 + lcol] = acc[mt][nt][3];
                }
            }
        }
        __syncthreads();
        unsigned wv = mb[col * 8 + c * 2 + (qt >> 2)];
        int bsh = (qt & 3) * 8;
        #pragma unroll
        for (int i = 0; i < 8; ++i) {
            int lrow = qt * 8 + i;
            float sc = scl[lrow * 68 + col];
            sc = ((wv >> (bsh + i)) & 1u) ? sc : 0.0f;
            ins10(s10, i10, sc, a0g + c * 64 + lrow);
        }
    }

    __syncthreads();                            // scl dead; reuse for merge
    #pragma unroll
    for (int k = 0; k < 10; ++k) {
        ms[col * 80 + qt * 10 + k] = s10[k];
        mi[col * 80 + qt * 10 + k] = i10[k];
    }
    __syncthreads();
    if (t < 64) {
        float fs[10]; int fi[10];
        #pragma unroll
        for (int q = 0; q < 10; ++q) { fs[q] = -INFINITY; fi[q] = 0x7fffffff; }
        for (int j = 0; j < 80; ++j)
            ins10(fs, fi, ms[t * 80 + j], mi[t * 80 + j]);
        size_t base = ((size_t)(b0 + t) * NTILES + gatile) * 10;
        #pragma unroll
        for (int k = 0; k < 10; ++k) { cs[base + k] = fs[k]; ci[base + k] = fi[k]; }
    }
}

// ---------------------------------------------------------------------------
// Per-row: merge 5000 candidates -> top-32 (f32), fp64 rescore, final top-10.
// ---------------------------------------------------------------------------
__global__ __launch_bounds__(256) void merge_rescore_k(
    const float* __restrict__ cs, const int* __restrict__ ci,
    const float* __restrict__ P, const float* __restrict__ ANS,
    const double* __restrict__ invn64, const float* __restrict__ mask,
    float* __restrict__ out)
{
    __shared__ float  ls[CAND_PER_ROW];
    __shared__ int    li[CAND_PER_ROW];
    __shared__ float  rrs[4];
    __shared__ int    rri[4], rrp[4];
    __shared__ int    topi_s[32];
    __shared__ double tops_s[32];
    __shared__ int    fin_s[10];
    int row = blockIdx.x, tid = threadIdx.x;

    const float* csr = cs + (size_t)row * CAND_PER_ROW;
    const int*   cir = ci + (size_t)row * CAND_PER_ROW;
    for (int i = tid; i < CAND_PER_ROW; i += 256) { ls[i] = csr[i]; li[i] = cir[i]; }
    __syncthreads();

    for (int it = 0; it < 32; ++it) {
        float bsv = -INFINITY; int bi = 0x7fffffff, bp = -1;
        for (int i = tid; i < CAND_PER_ROW; i += 256) {
            float s = ls[i];
            if (s > bsv || (s == bsv && li[i] < bi)) { bsv = s; bi = li[i]; bp = i; }
        }
        #pragma unroll
        for (int o = 32; o; o >>= 1) {
            float os = __shfl_down(bsv, o);
            int oi = __shfl_down(bi, o);
            int op = __shfl_down(bp, o);
            if (os > bsv || (os == bsv && oi < bi)) { bsv = os; bi = oi; bp = op; }
        }
        if ((tid & 63) == 0) { int w = tid >> 6; rrs[w] = bsv; rri[w] = bi; rrp[w] = bp; }
        __syncthreads();
        if (tid == 0) {
            for (int w = 1; w < 4; ++w)
                if (rrs[w] > bsv || (rrs[w] == bsv && rri[w] < bi)) {
                    bsv = rrs[w]; bi = rri[w]; bp = rrp[w];
                }
            topi_s[it] = bi;
            ls[bp] = -INFINITY;
        }
        __syncthreads();
    }

    int c = tid >> 3, part = tid & 7;
    int aidx = topi_s[c];
    const float4* p4 = (const float4*)(P + (size_t)row * DIM);
    const float4* a4 = (const float4*)(ANS + (size_t)aidx * DIM);
    double sum = 0.0;
    #pragma unroll 4
    for (int i = 0; i < 24; ++i) {
        float4 pv = p4[part * 24 + i];
        float4 av = a4[part * 24 + i];
        sum += (double)pv.x * av.x + (double)pv.y * av.y
             + (double)pv.z * av.z + (double)pv.w * av.w;
    }
    #pragma unroll
    for (int o = 4; o; o >>= 1) sum += __shfl_down(sum, o, 8);
    if (part == 0) {
        float m = mask[(size_t)row * NANS + aidx];
        tops_s[c] = sum * invn64[aidx] * (double)m;
    }
    __syncthreads();

    if (tid == 0) {
        unsigned used = 0;
        for (int k = 0; k < 10; ++k) {
            int bj = -1;
            for (int j = 0; j < 32; ++j) {
                if (used & (1u << j)) continue;
                if (bj < 0 || tops_s[j] > tops_s[bj] ||
                    (tops_s[j] == tops_s[bj] && topi_s[j] < topi_s[bj])) bj = j;
            }
            used |= 1u << bj;
            out[(size_t)row * 10 + k] = (float)tops_s[bj];
            out[10240 + (size_t)row * 10 + k] = (float)topi_s[bj];
            fin_s[k] = topi_s[bj];
        }
    }
    __syncthreads();

    for (int k = 0; k < 10; ++k) {
        int id = fin_s[k];
        const float* arow = ANS + (size_t)id * DIM;
        float* orow = out + 20480 + ((size_t)(row * 10 + k)) * DIM;
        for (int d = tid; d < DIM; d += 256) orow[d] = arow[d];
    }
}

// ---------------------------------------------------------------------------
extern "C" void kernel_launch(void* const* d_in, const int* in_sizes, int n_in,
                              void* d_out, int out_size, void* d_ws, size_t ws_size,
                              hipStream_t stream)
{
    (void)in_sizes; (void)n_in; (void)out_size;
    const float* visual = (const float*)d_in[0];
    const float* mask   = (const float*)d_in[2];
    const float* ans    = (const float*)d_in[3];
    const float* wv = (const float*)d_in[8];
    const float* bv = (const float*)d_in[9];
    const float* wo = (const float*)d_in[10];
    const float* bo = (const float*)d_in[11];
    const float* fw = (const float*)d_in[12];
    const float* fb = (const float*)d_in[13];
    const float* lg = (const float*)d_in[14];
    const float* lb = (const float*)d_in[15];
    const float* sw = (const float*)d_in[16];
    const float* sb = (const float*)d_in[17];
    float* out = (float*)d_out;

    // ---- workspace layout: persistent first, transient+AB share the tail ----
    char* w = (char*)d_ws;
    float*    P        = (float*)w;    w += (size_t)BATCH * DIM * 4;
    short*    Pb       = (short*)w;    w += (size_t)BATCH * DIM * 2;
    double*   invn64   = (double*)w;   w += (size_t)NANS * 8;
    float*    cs       = (float*)w;    w += (size_t)BATCH * CAND_PER_ROW * 4;
    int*      ci       = (int*)w;      w += (size_t)BATCH * CAND_PER_ROW * 4;
    unsigned* bits     = (unsigned*)w; w += (size_t)BATCH * NWORDS * 4;
    char*     tail     = w;            // transient region start
    float*    fused_in = (float*)tail;
    float*    v        = fused_in + (size_t)BATCH * 1536;
    float*    h        = v + (size_t)BATCH * DIM;
    short*    AB       = (short*)tail; // aliases fused_in/v/h AFTER they die

    size_t used = (size_t)(tail - (char*)d_ws);
    size_t atile_bytes = (size_t)256 * DIM * 2;                // 393216
    size_t avail = (ws_size > used) ? (ws_size - used) : atile_bytes;
    int CA = (int)(avail / atile_bytes);
    if (CA < 1) CA = 1;
    if (CA > NTILES) CA = NTILES;
    int nch = (NTILES + CA - 1) / CA;

    copy_visual_k<<<512, 256, 0, stream>>>(visual, fused_in);
    gemm_bias_k<<<dim3(16, 12), 256, 0, stream>>>(visual, DIM, wv, bv, v, DIM, DIM);
    gemm_bias_k<<<dim3(16, 12), 256, 0, stream>>>(v, DIM, wo, bo, fused_in + DIM, 1536, DIM);
    gemm_bias_k<<<dim3(16, 12), 256, 0, stream>>>(fused_in, 1536, fw, fb, h, DIM, 1536);
    ln_gelu_k<<<BATCH, 256, 0, stream>>>(h, lg, lb);
    gemm_bias_k<<<dim3(16, 12), 256, 0, stream>>>(h, DIM, sw, sb, P, DIM, DIM);
    l2norm_bf_k<<<BATCH, 256, 0, stream>>>(P, Pb);
    prep_mask_k<<<BATCH, 256, 0, stream>>>(mask, bits);
    // ---- upstream transient buffers are dead from here; AB may reuse them ----

    for (int ch = 0; ch < nch; ++ch) {
        int atile0 = ch * CA;
        int catiles = NTILES - atile0; if (catiles > CA) catiles = CA;
        int nrows = catiles * 256;
        prep_ans_k<<<(nrows + 3) / 4, 256, 0, stream>>>(ans, atile0 * 256, nrows,
                                                        invn64, AB);
        big3_k<<<catiles * 16, 512, 0, stream>>>(Pb, AB, bits, cs, ci,
                                                 atile0, catiles);
    }

    merge_rescore_k<<<BATCH, 256, 0, stream>>>(cs, ci, P, ans, invn64, mask, out);
}

// Round 6
// 4231.730 us; speedup vs baseline: 1.0175x; 1.0175x over previous
//
#include <hip/hip_runtime.h>
#include <math.h>

#define DIM    768
#define BATCH  1024
#define NANS   128000
#define NTILES 500              // 256-answer tiles
#define CAND_PER_ROW (NTILES*10)
#define NWORDS 4000             // mask bit-words per batch row (128000/32)

typedef short  bf16x8 __attribute__((ext_vector_type(8)));
typedef float  f32x4  __attribute__((ext_vector_type(4)));

__device__ __forceinline__ short f2bf(float x)
{
    unsigned u = __builtin_bit_cast(unsigned, x);
    u += 0x7fffu + ((u >> 16) & 1u);          // RNE (no NaN inputs here)
    return (short)(u >> 16);
}

// sorted-descending top-10 insertion (branchless swap chain, static indices)
__device__ __forceinline__ void ins10(float (&s)[10], int (&ix)[10], float v, int vi)
{
    if (v > s[9] || (v == s[9] && vi < ix[9])) {
        s[9] = v; ix[9] = vi;
        #pragma unroll
        for (int q = 9; q > 0; --q) {
            bool sw = (s[q] > s[q-1]) || (s[q] == s[q-1] && ix[q] < ix[q-1]);
            float ts = s[q-1]; int ti = ix[q-1];
            s[q-1] = sw ? s[q] : s[q-1]; ix[q-1] = sw ? ix[q] : ix[q-1];
            s[q]   = sw ? ts   : s[q];   ix[q]   = sw ? ti   : ix[q];
        }
    }
}

// ---------------------------------------------------------------------------
// Upstream GEMM: C[M,N] = A[M,K] @ W[N,K]^T + bias   (fp32)
// ---------------------------------------------------------------------------
__global__ __launch_bounds__(256, 2) void gemm_bias_k(
    const float* __restrict__ A, int lda,
    const float* __restrict__ W,
    const float* __restrict__ bias,
    float* __restrict__ C, int ldc, int K)
{
    __shared__ float as[32][68];
    __shared__ float bs[32][68];
    int m0 = blockIdx.x * 64, n0 = blockIdx.y * 64;
    int tid = threadIdx.x;
    int tm = tid & 15, tn = tid >> 4;
    int sr = tid >> 3, skq = tid & 7;
    float acc[4][4] = {};
    for (int k0 = 0; k0 < K; k0 += 32) {
        __syncthreads();
        #pragma unroll
        for (int p = 0; p < 2; ++p) {
            int r = sr + 32 * p;
            float4 av = *(const float4*)&A[(size_t)(m0 + r) * lda + k0 + skq * 4];
            as[skq*4+0][r] = av.x; as[skq*4+1][r] = av.y;
            as[skq*4+2][r] = av.z; as[skq*4+3][r] = av.w;
            float4 wv = *(const float4*)&W[(size_t)(n0 + r) * K + k0 + skq * 4];
            bs[skq*4+0][r] = wv.x; bs[skq*4+1][r] = wv.y;
            bs[skq*4+2][r] = wv.z; bs[skq*4+3][r] = wv.w;
        }
        __syncthreads();
        #pragma unroll 8
        for (int k = 0; k < 32; ++k) {
            float a4[4], b4[4];
            *(float4*)a4 = *(const float4*)&as[k][tm*4];
            *(float4*)b4 = *(const float4*)&bs[k][tn*4];
            #pragma unroll
            for (int i = 0; i < 4; ++i)
                #pragma unroll
                for (int j = 0; j < 4; ++j)
                    acc[i][j] = fmaf(a4[i], b4[j], acc[i][j]);
        }
    }
    float4 bv4 = *(const float4*)&bias[n0 + tn*4];
    #pragma unroll
    for (int i = 0; i < 4; ++i) {
        float4 c4;
        c4.x = acc[i][0] + bv4.x; c4.y = acc[i][1] + bv4.y;
        c4.z = acc[i][2] + bv4.z; c4.w = acc[i][3] + bv4.w;
        *(float4*)&C[(size_t)(m0 + tm*4 + i) * ldc + n0 + tn*4] = c4;
    }
}

// ---------------------------------------------------------------------------
__global__ void copy_visual_k(const float* __restrict__ src, float* __restrict__ dst)
{
    int idx = blockIdx.x * 256 + threadIdx.x;          // float4 index
    const int total = BATCH * (DIM / 4);
    for (; idx < total; idx += 512 * 256) {
        int b = idx / (DIM / 4), c = idx % (DIM / 4);
        ((float4*)dst)[(size_t)b * (1536 / 4) + c] = ((const float4*)src)[idx];
    }
}

// ---------------------------------------------------------------------------
__device__ __forceinline__ float block_sum(float v, float* red)
{
    #pragma unroll
    for (int o = 32; o; o >>= 1) v += __shfl_down(v, o);
    if ((threadIdx.x & 63) == 0) red[threadIdx.x >> 6] = v;
    __syncthreads();
    float r = red[0] + red[1] + red[2] + red[3];
    __syncthreads();
    return r;
}

__global__ __launch_bounds__(256) void ln_gelu_k(float* __restrict__ H,
        const float* __restrict__ g, const float* __restrict__ b)
{
    __shared__ float red[4];
    int row = blockIdx.x, tid = threadIdx.x;
    float* hr = H + (size_t)row * DIM;
    float v0 = hr[tid], v1 = hr[tid + 256], v2 = hr[tid + 512];
    float mu = block_sum(v0 + v1 + v2, red) * (1.0f / 768.0f);
    float d0 = v0 - mu, d1 = v1 - mu, d2 = v2 - mu;
    float var = block_sum(d0*d0 + d1*d1 + d2*d2, red) * (1.0f / 768.0f);
    float rinv = 1.0f / sqrtf(var + 1e-5f);
    #pragma unroll
    for (int q = 0; q < 3; ++q) {
        int d = tid + 256 * q;
        float dd = (q == 0 ? d0 : (q == 1 ? d1 : d2));
        float y = dd * rinv * g[d] + b[d];
        hr[d] = 0.5f * y * (1.0f + erff(y * 0.70710678118654752f));
    }
}

// l2-normalize P in place, also emit bf16 copy
__global__ __launch_bounds__(256) void l2norm_bf_k(float* __restrict__ P,
        short* __restrict__ Pb)
{
    __shared__ float red[4];
    int row = blockIdx.x, tid = threadIdx.x;
    float* pr = P + (size_t)row * DIM;
    short* pb = Pb + (size_t)row * DIM;
    float v0 = pr[tid], v1 = pr[tid + 256], v2 = pr[tid + 512];
    float ss = block_sum(v0*v0 + v1*v1 + v2*v2, red);
    float inv = 1.0f / fmaxf(sqrtf(ss), 1e-12f);
    v0 *= inv; v1 *= inv; v2 *= inv;
    pr[tid] = v0; pr[tid + 256] = v1; pr[tid + 512] = v2;
    pb[tid] = f2bf(v0); pb[tid + 256] = f2bf(v1); pb[tid + 512] = f2bf(v2);
}

// ---------------------------------------------------------------------------
// prep_ans: fp64 row norm -> inv64[row]; write unit-normalized bf16 rows into
// the chunk buffer AB (local row r = global row0+r). One wave per row.
// ---------------------------------------------------------------------------
__global__ __launch_bounds__(256) void prep_ans_k(
    const float* __restrict__ ANS, int row0, int nrows,
    double* __restrict__ inv64, short* __restrict__ AB)
{
    int r = blockIdx.x * 4 + (threadIdx.x >> 6);
    if (r >= nrows) return;
    int row = row0 + r;
    int lane = threadIdx.x & 63;
    const float4* a4 = (const float4*)(ANS + (size_t)row * DIM);
    float4 x0 = a4[lane], x1 = a4[lane + 64], x2 = a4[lane + 128];
    double ss = (double)x0.x*x0.x + (double)x0.y*x0.y + (double)x0.z*x0.z + (double)x0.w*x0.w
              + (double)x1.x*x1.x + (double)x1.y*x1.y + (double)x1.z*x1.z + (double)x1.w*x1.w
              + (double)x2.x*x2.x + (double)x2.y*x2.y + (double)x2.z*x2.z + (double)x2.w*x2.w;
    #pragma unroll
    for (int o = 32; o; o >>= 1) ss += __shfl_xor(ss, o);
    double inv = 1.0 / fmax(sqrt(ss), 1e-12);
    if (lane == 0) inv64[row] = inv;
    float invf = (float)inv;
    short* ob = AB + (size_t)r * DIM;
    ushort4 o0, o1, o2;
    o0.x = (unsigned short)f2bf(x0.x*invf); o0.y = (unsigned short)f2bf(x0.y*invf);
    o0.z = (unsigned short)f2bf(x0.z*invf); o0.w = (unsigned short)f2bf(x0.w*invf);
    o1.x = (unsigned short)f2bf(x1.x*invf); o1.y = (unsigned short)f2bf(x1.y*invf);
    o1.z = (unsigned short)f2bf(x1.z*invf); o1.w = (unsigned short)f2bf(x1.w*invf);
    o2.x = (unsigned short)f2bf(x2.x*invf); o2.y = (unsigned short)f2bf(x2.y*invf);
    o2.z = (unsigned short)f2bf(x2.z*invf); o2.w = (unsigned short)f2bf(x2.w*invf);
    *(ushort4*)&ob[lane * 4]           = o0;
    *(ushort4*)&ob[(lane + 64) * 4]    = o1;
    *(ushort4*)&ob[(lane + 128) * 4]   = o2;
}

// ---------------------------------------------------------------------------
// prep_mask: float mask [1024][128000] -> bits [1024][4000]
// ---------------------------------------------------------------------------
__global__ __launch_bounds__(256) void prep_mask_k(
    const float* __restrict__ mask, unsigned* __restrict__ bits)
{
    int row = blockIdx.x;
    const float* mr = mask + (size_t)row * NANS;
    unsigned* br = bits + (size_t)row * NWORDS;
    for (int w = threadIdx.x; w < NWORDS; w += 256) {
        const float4* p = (const float4*)(mr + w * 32);
        unsigned b = 0;
        #pragma unroll
        for (int q = 0; q < 8; ++q) {
            float4 v = p[q];
            b |= ((unsigned)(v.x != 0.f)) << (q*4+0);
            b |= ((unsigned)(v.y != 0.f)) << (q*4+1);
            b |= ((unsigned)(v.z != 0.f)) << (q*4+2);
            b |= ((unsigned)(v.w != 0.f)) << (q*4+3);
        }
        br[w] = b;
    }
}

// ---------------------------------------------------------------------------
// Big MFMA kernel v3: 256 answers x 64 batch per block, 512 thr (8 waves,
// each owning a 32x64 sub-tile -> acc[2][4] = 32 VGPRs). BK=64, reg staging,
// bitmask epilogue, per-(row, 256-answer-tile) top-10 shortlist.
// NOTE launch_bounds min-occupancy: CUDA semantics = min BLOCKS/CU. (512,4)
// capped VGPRs at 64 -> acc spill -> 8 GB scratch writes (round 5). (512,2)
// gives a 128-VGPR cap; demand ~100 fits, 2 blocks/CU from LDS+VGPR anyway.
// ---------------------------------------------------------------------------
__global__ __launch_bounds__(512, 2) void big3_k(
    const short* __restrict__ Pb,       // [1024][768] unit-norm bf16
    const short* __restrict__ AB,       // chunk [catiles*256][768] unit-norm bf16
    const unsigned* __restrict__ bits,  // [1024][4000]
    float* __restrict__ cs, int* __restrict__ ci,
    int atile0, int catiles)
{
    __shared__ __align__(16) char smem[48128];
    short* a_sh = (short*)smem;                 // [256][72] = 36864 B
    short* b_sh = (short*)(smem + 36864);       // [64][72]  =  9216 B
    unsigned* mb = (unsigned*)(smem + 46080);   // [64][8]   =  2048 B
    float* scl = (float*)smem;                  // reuse: [64 ans][68] = 17408 B
    float* ms  = (float*)smem;                  // reuse: [64][80] f32
    int*   mi  = (int*)(smem + 20480);          // reuse: [64][80] i32

    // XCD swizzle: blocks with equal bid%8 (one XCD) share an answer tile
    int bid = blockIdx.x;
    int cpx = catiles * 2;                      // blocks per XCD
    int v = (bid & 7) * cpx + (bid >> 3);       // bijective (nwg%8==0)
    int atile = v >> 4, btile = v & 15;
    int gatile = atile0 + atile;
    int a0l = atile * 256, a0g = gatile * 256, b0 = btile * 64;

    int t = threadIdx.x;
    int lane = t & 63, wid = t >> 6;
    int lr = lane & 15, lg = lane >> 4;

    // stage mask bits: 64 rows x 8 words = 512, one per thread
    mb[t] = bits[(size_t)(b0 + (t >> 3)) * NWORDS + gatile * 8 + (t & 7)];

    // staging: thread owns (srow 0..63, sseg); A rows srow+64p p=0..3, B p=0
    int srow = t >> 3, sseg = (t & 7) * 8;
    const short* gA = AB + (size_t)(a0l + srow) * DIM + sseg;
    const short* gB = Pb + (size_t)(b0  + srow) * DIM + sseg;
    short* wA = a_sh + srow * 72 + sseg;
    short* wB = b_sh + srow * 72 + sseg;

    f32x4 acc[2][4];
    #pragma unroll
    for (int i = 0; i < 2; ++i)
        #pragma unroll
        for (int j = 0; j < 4; ++j)
            acc[i][j] = (f32x4){0.f, 0.f, 0.f, 0.f};

    bf16x8 rA0 = *(const bf16x8*)(gA);
    bf16x8 rA1 = *(const bf16x8*)(gA + 64 * DIM);
    bf16x8 rA2 = *(const bf16x8*)(gA + 128 * DIM);
    bf16x8 rA3 = *(const bf16x8*)(gA + 192 * DIM);
    bf16x8 rB0 = *(const bf16x8*)(gB);

    for (int kt = 0; kt < 12; ++kt) {
        __syncthreads();                        // prev MFMA reads done
        *(bf16x8*)(wA)            = rA0;
        *(bf16x8*)(wA +  64 * 72) = rA1;
        *(bf16x8*)(wA + 128 * 72) = rA2;
        *(bf16x8*)(wA + 192 * 72) = rA3;
        *(bf16x8*)(wB)            = rB0;
        if (kt < 11) {                          // issue next K-tile early
            int ko = (kt + 1) * 64;
            rA0 = *(const bf16x8*)(gA + ko);
            rA1 = *(const bf16x8*)(gA + 64 * DIM + ko);
            rA2 = *(const bf16x8*)(gA + 128 * DIM + ko);
            rA3 = *(const bf16x8*)(gA + 192 * DIM + ko);
            rB0 = *(const bf16x8*)(gB + ko);
        }
        __syncthreads();                        // writes visible
        #pragma unroll
        for (int h = 0; h < 2; ++h) {
            bf16x8 af[2], bg[4];
            #pragma unroll
            for (int mt = 0; mt < 2; ++mt)
                af[mt] = *(const bf16x8*)(a_sh + (wid*32 + mt*16 + lr) * 72 + h*32 + lg*8);
            #pragma unroll
            for (int nt = 0; nt < 4; ++nt)
                bg[nt] = *(const bf16x8*)(b_sh + (nt*16 + lr) * 72 + h*32 + lg*8);
            #pragma unroll
            for (int mt = 0; mt < 2; ++mt)
                #pragma unroll
                for (int nt = 0; nt < 4; ++nt)
                    acc[mt][nt] = __builtin_amdgcn_mfma_f32_16x16x32_bf16(
                        af[mt], bg[nt], acc[mt][nt], 0, 0, 0);
        }
    }

    // ---- epilogue: bitmask + per-column top-10 over the 256-answer tile ----
    float s10[10]; int i10[10];
    #pragma unroll
    for (int q = 0; q < 10; ++q) { s10[q] = -INFINITY; i10[q] = 0x7fffffff; }
    int col = t & 63, qt = t >> 6;              // 8 groups x 8 answers each

    for (int c = 0; c < 4; ++c) {               // 64-answer chunks
        __syncthreads();
        if ((wid >> 1) == c) {                  // waves 2c, 2c+1 dump
            int sub = wid & 1;
            #pragma unroll
            for (int nt = 0; nt < 4; ++nt) {
                int lcol = nt * 16 + lr;
                #pragma unroll
                for (int mt = 0; mt < 2; ++mt) {
                    int lrow = sub * 32 + mt * 16 + lg * 4;
                    scl[(lrow + 0) * 68 + lcol] = acc[mt][nt][0];
                    scl[(lrow + 1) * 68 + lcol] = acc[mt][nt][1];
                    scl[(lrow + 2) * 68 + lcol] = acc[mt][nt][2];
                    scl[(lrow + 3) * 68 + lcol] = acc[mt][nt][3];
                }
            }
        }
        __syncthreads();
        unsigned wv = mb[col * 8 + c * 2 + (qt >> 2)];
        int bsh = (qt & 3) * 8;
        #pragma unroll
        for (int i = 0; i < 8; ++i) {
            int lrow = qt * 8 + i;
            float sc = scl[lrow * 68 + col];
            sc = ((wv >> (bsh + i)) & 1u) ? sc : 0.0f;
            ins10(s10, i10, sc, a0g + c * 64 + lrow);
        }
    }

    __syncthreads();                            // scl dead; reuse for merge
    #pragma unroll
    for (int k = 0; k < 10; ++k) {
        ms[col * 80 + qt * 10 + k] = s10[k];
        mi[col * 80 + qt * 10 + k] = i10[k];
    }
    __syncthreads();
    if (t < 64) {
        float fs[10]; int fi[10];
        #pragma unroll
        for (int q = 0; q < 10; ++q) { fs[q] = -INFINITY; fi[q] = 0x7fffffff; }
        for (int j = 0; j < 80; ++j)
            ins10(fs, fi, ms[t * 80 + j], mi[t * 80 + j]);
        size_t base = ((size_t)(b0 + t) * NTILES + gatile) * 10;
        #pragma unroll
        for (int k = 0; k < 10; ++k) { cs[base + k] = fs[k]; ci[base + k] = fi[k]; }
    }
}

// ---------------------------------------------------------------------------
// Per-row: merge 5000 candidates -> top-32 (f32), fp64 rescore, final top-10.
// ---------------------------------------------------------------------------
__global__ __launch_bounds__(256) void merge_rescore_k(
    const float* __restrict__ cs, const int* __restrict__ ci,
    const float* __restrict__ P, const float* __restrict__ ANS,
    const double* __restrict__ invn64, const float* __restrict__ mask,
    float* __restrict__ out)
{
    __shared__ float  ls[CAND_PER_ROW];
    __shared__ int    li[CAND_PER_ROW];
    __shared__ float  rrs[4];
    __shared__ int    rri[4], rrp[4];
    __shared__ int    topi_s[32];
    __shared__ double tops_s[32];
    __shared__ int    fin_s[10];
    int row = blockIdx.x, tid = threadIdx.x;

    const float* csr = cs + (size_t)row * CAND_PER_ROW;
    const int*   cir = ci + (size_t)row * CAND_PER_ROW;
    for (int i = tid; i < CAND_PER_ROW; i += 256) { ls[i] = csr[i]; li[i] = cir[i]; }
    __syncthreads();

    for (int it = 0; it < 32; ++it) {
        float bsv = -INFINITY; int bi = 0x7fffffff, bp = -1;
        for (int i = tid; i < CAND_PER_ROW; i += 256) {
            float s = ls[i];
            if (s > bsv || (s == bsv && li[i] < bi)) { bsv = s; bi = li[i]; bp = i; }
        }
        #pragma unroll
        for (int o = 32; o; o >>= 1) {
            float os = __shfl_down(bsv, o);
            int oi = __shfl_down(bi, o);
            int op = __shfl_down(bp, o);
            if (os > bsv || (os == bsv && oi < bi)) { bsv = os; bi = oi; bp = op; }
        }
        if ((tid & 63) == 0) { int w = tid >> 6; rrs[w] = bsv; rri[w] = bi; rrp[w] = bp; }
        __syncthreads();
        if (tid == 0) {
            for (int w = 1; w < 4; ++w)
                if (rrs[w] > bsv || (rrs[w] == bsv && rri[w] < bi)) {
                    bsv = rrs[w]; bi = rri[w]; bp = rrp[w];
                }
            topi_s[it] = bi;
            ls[bp] = -INFINITY;
        }
        __syncthreads();
    }

    int c = tid >> 3, part = tid & 7;
    int aidx = topi_s[c];
    const float4* p4 = (const float4*)(P + (size_t)row * DIM);
    const float4* a4 = (const float4*)(ANS + (size_t)aidx * DIM);
    double sum = 0.0;
    #pragma unroll 4
    for (int i = 0; i < 24; ++i) {
        float4 pv = p4[part * 24 + i];
        float4 av = a4[part * 24 + i];
        sum += (double)pv.x * av.x + (double)pv.y * av.y
             + (double)pv.z * av.z + (double)pv.w * av.w;
    }
    #pragma unroll
    for (int o = 4; o; o >>= 1) sum += __shfl_down(sum, o, 8);
    if (part == 0) {
        float m = mask[(size_t)row * NANS + aidx];
        tops_s[c] = sum * invn64[aidx] * (double)m;
    }
    __syncthreads();

    if (tid == 0) {
        unsigned used = 0;
        for (int k = 0; k < 10; ++k) {
            int bj = -1;
            for (int j = 0; j < 32; ++j) {
                if (used & (1u << j)) continue;
                if (bj < 0 || tops_s[j] > tops_s[bj] ||
                    (tops_s[j] == tops_s[bj] && topi_s[j] < topi_s[bj])) bj = j;
            }
            used |= 1u << bj;
            out[(size_t)row * 10 + k] = (float)tops_s[bj];
            out[10240 + (size_t)row * 10 + k] = (float)topi_s[bj];
            fin_s[k] = topi_s[bj];
        }
    }
    __syncthreads();

    for (int k = 0; k < 10; ++k) {
        int id = fin_s[k];
        const float* arow = ANS + (size_t)id * DIM;
        float* orow = out + 20480 + ((size_t)(row * 10 + k)) * DIM;
        for (int d = tid; d < DIM; d += 256) orow[d] = arow[d];
    }
}

// ---------------------------------------------------------------------------
extern "C" void kernel_launch(void* const* d_in, const int* in_sizes, int n_in,
                              void* d_out, int out_size, void* d_ws, size_t ws_size,
                              hipStream_t stream)
{
    (void)in_sizes; (void)n_in; (void)out_size;
    const float* visual = (const float*)d_in[0];
    const float* mask   = (const float*)d_in[2];
    const float* ans    = (const float*)d_in[3];
    const float* wv = (const float*)d_in[8];
    const float* bv = (const float*)d_in[9];
    const float* wo = (const float*)d_in[10];
    const float* bo = (const float*)d_in[11];
    const float* fw = (const float*)d_in[12];
    const float* fb = (const float*)d_in[13];
    const float* lg = (const float*)d_in[14];
    const float* lb = (const float*)d_in[15];
    const float* sw = (const float*)d_in[16];
    const float* sb = (const float*)d_in[17];
    float* out = (float*)d_out;

    // ---- workspace layout: persistent first, transient+AB share the tail ----
    char* w = (char*)d_ws;
    float*    P        = (float*)w;    w += (size_t)BATCH * DIM * 4;
    short*    Pb       = (short*)w;    w += (size_t)BATCH * DIM * 2;
    double*   invn64   = (double*)w;   w += (size_t)NANS * 8;
    float*    cs       = (float*)w;    w += (size_t)BATCH * CAND_PER_ROW * 4;
    int*      ci       = (int*)w;      w += (size_t)BATCH * CAND_PER_ROW * 4;
    unsigned* bits     = (unsigned*)w; w += (size_t)BATCH * NWORDS * 4;
    char*     tail     = w;            // transient region start
    float*    fused_in = (float*)tail;
    float*    v        = fused_in + (size_t)BATCH * 1536;
    float*    h        = v + (size_t)BATCH * DIM;
    short*    AB       = (short*)tail; // aliases fused_in/v/h AFTER they die

    size_t used = (size_t)(tail - (char*)d_ws);
    size_t atile_bytes = (size_t)256 * DIM * 2;                // 393216
    size_t avail = (ws_size > used) ? (ws_size - used) : atile_bytes;
    int CA = (int)(avail / atile_bytes);
    if (CA < 1) CA = 1;
    if (CA > NTILES) CA = NTILES;
    int nch = (NTILES + CA - 1) / CA;

    copy_visual_k<<<512, 256, 0, stream>>>(visual, fused_in);
    gemm_bias_k<<<dim3(16, 12), 256, 0, stream>>>(visual, DIM, wv, bv, v, DIM, DIM);
    gemm_bias_k<<<dim3(16, 12), 256, 0, stream>>>(v, DIM, wo, bo, fused_in + DIM, 1536, DIM);
    gemm_bias_k<<<dim3(16, 12), 256, 0, stream>>>(fused_in, 1536, fw, fb, h, DIM, 1536);
    ln_gelu_k<<<BATCH, 256, 0, stream>>>(h, lg, lb);
    gemm_bias_k<<<dim3(16, 12), 256, 0, stream>>>(h, DIM, sw, sb, P, DIM, DIM);
    l2norm_bf_k<<<BATCH, 256, 0, stream>>>(P, Pb);
    prep_mask_k<<<BATCH, 256, 0, stream>>>(mask, bits);
    // ---- upstream transient buffers are dead from here; AB may reuse them ----

    for (int ch = 0; ch < nch; ++ch) {
        int atile0 = ch * CA;
        int catiles = NTILES - atile0; if (catiles > CA) catiles = CA;
        int nrows = catiles * 256;
        prep_ans_k<<<(nrows + 3) / 4, 256, 0, stream>>>(ans, atile0 * 256, nrows,
                                                        invn64, AB);
        big3_k<<<catiles * 16, 512, 0, stream>>>(Pb, AB, bits, cs, ci,
                                                 atile0, catiles);
    }

    merge_rescore_k<<<BATCH, 256, 0, stream>>>(cs, ci, P, ans, invn64, mask, out);
}

// Round 7
// 4129.667 us; speedup vs baseline: 1.0426x; 1.0247x over previous
//
#include <hip/hip_runtime.h>
#include <math.h>

#define DIM    768
#define BATCH  1024
#define NANS   128000
#define NT128  1000             // 128-answer shortlist tiles
#define CAND2  (NT128*10)       // 10000 shortlist candidates per row
#define NWORDS 4000             // mask bit-words per batch row (128000/32)

typedef short  bf16x8 __attribute__((ext_vector_type(8)));
typedef float  f32x4  __attribute__((ext_vector_type(4)));

__device__ __forceinline__ short f2bf(float x)
{
    unsigned u = __builtin_bit_cast(unsigned, x);
    u += 0x7fffu + ((u >> 16) & 1u);          // RNE (no NaN inputs here)
    return (short)(u >> 16);
}

__device__ __forceinline__ void gload16(const void* g, void* l)
{
    __builtin_amdgcn_global_load_lds(
        (const __attribute__((address_space(1))) void*)g,
        (__attribute__((address_space(3))) void*)l, 16, 0, 0);
}

// sorted-descending top-10 insertion (static indices only)
__device__ __forceinline__ void ins10(float (&s)[10], int (&ix)[10], float v, int vi)
{
    if (v > s[9] || (v == s[9] && vi < ix[9])) {
        s[9] = v; ix[9] = vi;
        #pragma unroll
        for (int q = 9; q > 0; --q) {
            bool sw = (s[q] > s[q-1]) || (s[q] == s[q-1] && ix[q] < ix[q-1]);
            float ts = s[q-1]; int ti = ix[q-1];
            s[q-1] = sw ? s[q] : s[q-1]; ix[q-1] = sw ? ix[q] : ix[q-1];
            s[q]   = sw ? ts   : s[q];   ix[q]   = sw ? ti   : ix[q];
        }
    }
}

__device__ __forceinline__ void ins16(float (&s)[16], int (&ix)[16], float v, int vi)
{
    if (v > s[15] || (v == s[15] && vi < ix[15])) {
        s[15] = v; ix[15] = vi;
        #pragma unroll
        for (int q = 15; q > 0; --q) {
            bool sw = (s[q] > s[q-1]) || (s[q] == s[q-1] && ix[q] < ix[q-1]);
            float ts = s[q-1]; int ti = ix[q-1];
            s[q-1] = sw ? s[q] : s[q-1]; ix[q-1] = sw ? ix[q] : ix[q-1];
            s[q]   = sw ? ts   : s[q];   ix[q]   = sw ? ti   : ix[q];
        }
    }
}

// ---------------------------------------------------------------------------
// Upstream GEMM: C[M,N] = A[M,K] @ W[N,K]^T + bias   (fp32)
// ---------------------------------------------------------------------------
__global__ __launch_bounds__(256, 2) void gemm_bias_k(
    const float* __restrict__ A, int lda,
    const float* __restrict__ W,
    const float* __restrict__ bias,
    float* __restrict__ C, int ldc, int K)
{
    __shared__ float as[32][68];
    __shared__ float bs[32][68];
    int m0 = blockIdx.x * 64, n0 = blockIdx.y * 64;
    int tid = threadIdx.x;
    int tm = tid & 15, tn = tid >> 4;
    int sr = tid >> 3, skq = tid & 7;
    float acc[4][4] = {};
    for (int k0 = 0; k0 < K; k0 += 32) {
        __syncthreads();
        #pragma unroll
        for (int p = 0; p < 2; ++p) {
            int r = sr + 32 * p;
            float4 av = *(const float4*)&A[(size_t)(m0 + r) * lda + k0 + skq * 4];
            as[skq*4+0][r] = av.x; as[skq*4+1][r] = av.y;
            as[skq*4+2][r] = av.z; as[skq*4+3][r] = av.w;
            float4 wv = *(const float4*)&W[(size_t)(n0 + r) * K + k0 + skq * 4];
            bs[skq*4+0][r] = wv.x; bs[skq*4+1][r] = wv.y;
            bs[skq*4+2][r] = wv.z; bs[skq*4+3][r] = wv.w;
        }
        __syncthreads();
        #pragma unroll 8
        for (int k = 0; k < 32; ++k) {
            float a4[4], b4[4];
            *(float4*)a4 = *(const float4*)&as[k][tm*4];
            *(float4*)b4 = *(const float4*)&bs[k][tn*4];
            #pragma unroll
            for (int i = 0; i < 4; ++i)
                #pragma unroll
                for (int j = 0; j < 4; ++j)
                    acc[i][j] = fmaf(a4[i], b4[j], acc[i][j]);
        }
    }
    float4 bv4 = *(const float4*)&bias[n0 + tn*4];
    #pragma unroll
    for (int i = 0; i < 4; ++i) {
        float4 c4;
        c4.x = acc[i][0] + bv4.x; c4.y = acc[i][1] + bv4.y;
        c4.z = acc[i][2] + bv4.z; c4.w = acc[i][3] + bv4.w;
        *(float4*)&C[(size_t)(m0 + tm*4 + i) * ldc + n0 + tn*4] = c4;
    }
}

// ---------------------------------------------------------------------------
__global__ void copy_visual_k(const float* __restrict__ src, float* __restrict__ dst)
{
    int idx = blockIdx.x * 256 + threadIdx.x;          // float4 index
    const int total = BATCH * (DIM / 4);
    for (; idx < total; idx += 512 * 256) {
        int b = idx / (DIM / 4), c = idx % (DIM / 4);
        ((float4*)dst)[(size_t)b * (1536 / 4) + c] = ((const float4*)src)[idx];
    }
}

// ---------------------------------------------------------------------------
__device__ __forceinline__ float block_sum(float v, float* red)
{
    #pragma unroll
    for (int o = 32; o; o >>= 1) v += __shfl_down(v, o);
    if ((threadIdx.x & 63) == 0) red[threadIdx.x >> 6] = v;
    __syncthreads();
    float r = red[0] + red[1] + red[2] + red[3];
    __syncthreads();
    return r;
}

__global__ __launch_bounds__(256) void ln_gelu_k(float* __restrict__ H,
        const float* __restrict__ g, const float* __restrict__ b)
{
    __shared__ float red[4];
    int row = blockIdx.x, tid = threadIdx.x;
    float* hr = H + (size_t)row * DIM;
    float v0 = hr[tid], v1 = hr[tid + 256], v2 = hr[tid + 512];
    float mu = block_sum(v0 + v1 + v2, red) * (1.0f / 768.0f);
    float d0 = v0 - mu, d1 = v1 - mu, d2 = v2 - mu;
    float var = block_sum(d0*d0 + d1*d1 + d2*d2, red) * (1.0f / 768.0f);
    float rinv = 1.0f / sqrtf(var + 1e-5f);
    #pragma unroll
    for (int q = 0; q < 3; ++q) {
        int d = tid + 256 * q;
        float dd = (q == 0 ? d0 : (q == 1 ? d1 : d2));
        float y = dd * rinv * g[d] + b[d];
        hr[d] = 0.5f * y * (1.0f + erff(y * 0.70710678118654752f));
    }
}

// l2-normalize P in place, also emit bf16 copy
__global__ __launch_bounds__(256) void l2norm_bf_k(float* __restrict__ P,
        short* __restrict__ Pb)
{
    __shared__ float red[4];
    int row = blockIdx.x, tid = threadIdx.x;
    float* pr = P + (size_t)row * DIM;
    short* pb = Pb + (size_t)row * DIM;
    float v0 = pr[tid], v1 = pr[tid + 256], v2 = pr[tid + 512];
    float ss = block_sum(v0*v0 + v1*v1 + v2*v2, red);
    float inv = 1.0f / fmaxf(sqrtf(ss), 1e-12f);
    v0 *= inv; v1 *= inv; v2 *= inv;
    pr[tid] = v0; pr[tid + 256] = v1; pr[tid + 512] = v2;
    pb[tid] = f2bf(v0); pb[tid + 256] = f2bf(v1); pb[tid + 512] = f2bf(v2);
}

// ---------------------------------------------------------------------------
// prep_ans: fp64 row norm -> inv64[row]; unit-normalized bf16 rows into AB.
// ---------------------------------------------------------------------------
__global__ __launch_bounds__(256) void prep_ans_k(
    const float* __restrict__ ANS, int row0, int nrows,
    double* __restrict__ inv64, short* __restrict__ AB)
{
    int r = blockIdx.x * 4 + (threadIdx.x >> 6);
    if (r >= nrows) return;
    int row = row0 + r;
    int lane = threadIdx.x & 63;
    const float4* a4 = (const float4*)(ANS + (size_t)row * DIM);
    float4 x0 = a4[lane], x1 = a4[lane + 64], x2 = a4[lane + 128];
    double ss = (double)x0.x*x0.x + (double)x0.y*x0.y + (double)x0.z*x0.z + (double)x0.w*x0.w
              + (double)x1.x*x1.x + (double)x1.y*x1.y + (double)x1.z*x1.z + (double)x1.w*x1.w
              + (double)x2.x*x2.x + (double)x2.y*x2.y + (double)x2.z*x2.z + (double)x2.w*x2.w;
    #pragma unroll
    for (int o = 32; o; o >>= 1) ss += __shfl_xor(ss, o);
    double inv = 1.0 / fmax(sqrt(ss), 1e-12);
    if (lane == 0) inv64[row] = inv;
    float invf = (float)inv;
    short* ob = AB + (size_t)r * DIM;
    ushort4 o0, o1, o2;
    o0.x = (unsigned short)f2bf(x0.x*invf); o0.y = (unsigned short)f2bf(x0.y*invf);
    o0.z = (unsigned short)f2bf(x0.z*invf); o0.w = (unsigned short)f2bf(x0.w*invf);
    o1.x = (unsigned short)f2bf(x1.x*invf); o1.y = (unsigned short)f2bf(x1.y*invf);
    o1.z = (unsigned short)f2bf(x1.z*invf); o1.w = (unsigned short)f2bf(x1.w*invf);
    o2.x = (unsigned short)f2bf(x2.x*invf); o2.y = (unsigned short)f2bf(x2.y*invf);
    o2.z = (unsigned short)f2bf(x2.z*invf); o2.w = (unsigned short)f2bf(x2.w*invf);
    *(ushort4*)&ob[lane * 4]           = o0;
    *(ushort4*)&ob[(lane + 64) * 4]    = o1;
    *(ushort4*)&ob[(lane + 128) * 4]   = o2;
}

// ---------------------------------------------------------------------------
// prep_mask: float mask [1024][128000] -> bits [1024][4000]
// ---------------------------------------------------------------------------
__global__ __launch_bounds__(256) void prep_mask_k(
    const float* __restrict__ mask, unsigned* __restrict__ bits)
{
    int row = blockIdx.x;
    const float* mr = mask + (size_t)row * NANS;
    unsigned* br = bits + (size_t)row * NWORDS;
    for (int w = threadIdx.x; w < NWORDS; w += 256) {
        const float4* p = (const float4*)(mr + w * 32);
        unsigned b = 0;
        #pragma unroll
        for (int q = 0; q < 8; ++q) {
            float4 v = p[q];
            b |= ((unsigned)(v.x != 0.f)) << (q*4+0);
            b |= ((unsigned)(v.y != 0.f)) << (q*4+1);
            b |= ((unsigned)(v.z != 0.f)) << (q*4+2);
            b |= ((unsigned)(v.w != 0.f)) << (q*4+3);
        }
        br[w] = b;
    }
}

// ---------------------------------------------------------------------------
// big4_k: m97-structure MFMA GEMM + shortlist.
// 256 threads / 4 waves; tile 128 answers x 128 batch; BK=32; 24 K-steps;
// global_load_lds(16) staging into linear LDS [row][32]; 2 barriers/K-step.
// Epilogue: bitmask + per-batch-column top-10 over the 128-answer tile.
// ---------------------------------------------------------------------------
__global__ void big4_k(
    const short* __restrict__ Pb,       // [1024][768] unit-norm bf16
    const short* __restrict__ AB,       // chunk rows, unit-norm bf16
    const unsigned* __restrict__ bits,  // [1024][4000]
    float* __restrict__ cs, int* __restrict__ ci,
    int t128_0, int nt128)
{
    __shared__ __align__(16) char smem[35840];
    short* a_sh = (short*)smem;                 // [128][32] = 8192 B
    short* b_sh = (short*)(smem + 8192);        // [128][32] = 8192 B
    unsigned* mb = (unsigned*)(smem + 33792);   // [128][4]  = 2048 B
    float* scl = (float*)smem;                  // reuse: [64][132] = 33792 B
    float* ms  = (float*)smem;                  // reuse: [128][20]
    int*   mi  = (int*)(smem + 10240);          // reuse: [128][20]

    // XCD swizzle: blocks on one XCD share answer tiles (nwg % 8 == 0)
    int bid = blockIdx.x;
    int v = (bid & 7) * nt128 + (bid >> 3);
    int at = v >> 3, bt = v & 7;
    int gt = t128_0 + at;                       // global 128-tile id
    int a0l = at * 128, a0g = gt * 128, b0 = bt * 128;

    int t = threadIdx.x;
    int lane = t & 63, wid = t >> 6;
    int wm = wid & 1, wn = wid >> 1;            // 2x2 wave grid of 64x64
    int lr = lane & 15, lg = lane >> 4;

    // stage mask bits: 128 rows x 4 words
    mb[t]       = bits[(size_t)(b0 + (t >> 2)) * NWORDS + gt * 4 + (t & 3)];
    mb[t + 256] = bits[(size_t)(b0 + 64 + (t >> 2)) * NWORDS + gt * 4 + (t & 3)];

    // staging addresses: chunk c of 16 B; row = c>>2, seg = c&3; thread owns
    // chunks t (rows 0-63) and t+256 (rows 64-127) for both A and B.
    const char* gA0 = (const char*)(AB + (size_t)(a0l + (t >> 2)) * DIM + (t & 3) * 8);
    const char* gA1 = (const char*)(AB + (size_t)(a0l + 64 + (t >> 2)) * DIM + (t & 3) * 8);
    const char* gB0 = (const char*)(Pb + (size_t)(b0 + (t >> 2)) * DIM + (t & 3) * 8);
    const char* gB1 = (const char*)(Pb + (size_t)(b0 + 64 + (t >> 2)) * DIM + (t & 3) * 8);
    char* la0 = (char*)a_sh + t * 16;
    char* la1 = (char*)a_sh + 4096 + t * 16;
    char* lb0 = (char*)b_sh + t * 16;
    char* lb1 = (char*)b_sh + 4096 + t * 16;

    f32x4 acc[4][4];
    #pragma unroll
    for (int i = 0; i < 4; ++i)
        #pragma unroll
        for (int j = 0; j < 4; ++j)
            acc[i][j] = (f32x4){0.f, 0.f, 0.f, 0.f};

    for (int kt = 0; kt < 24; ++kt) {
        int kb = kt * 64;                       // byte offset in a 768-short row
        gload16(gA0 + kb, la0);
        gload16(gA1 + kb, la1);
        gload16(gB0 + kb, lb0);
        gload16(gB1 + kb, lb1);
        __syncthreads();                        // drain vmcnt + barrier
        bf16x8 af[4], bg[4];
        #pragma unroll
        for (int mt = 0; mt < 4; ++mt)
            af[mt] = *(const bf16x8*)(a_sh + (wm*64 + mt*16 + lr) * 32 + lg*8);
        #pragma unroll
        for (int nt = 0; nt < 4; ++nt)
            bg[nt] = *(const bf16x8*)(b_sh + (wn*64 + nt*16 + lr) * 32 + lg*8);
        #pragma unroll
        for (int mt = 0; mt < 4; ++mt)
            #pragma unroll
            for (int nt = 0; nt < 4; ++nt)
                acc[mt][nt] = __builtin_amdgcn_mfma_f32_16x16x32_bf16(
                    af[mt], bg[nt], acc[mt][nt], 0, 0, 0);
        __syncthreads();                        // reads done before next stage
    }

    // ---- epilogue: bitmask + per-column top-10 over 128 answers ----
    float s10[10]; int i10[10];
    #pragma unroll
    for (int q = 0; q < 10; ++q) { s10[q] = -INFINITY; i10[q] = 0x7fffffff; }
    int col = t & 127, qt = t >> 7;             // qt 0..1: 32 answers each

    for (int c = 0; c < 2; ++c) {               // 64-answer chunks
        __syncthreads();
        if (wm == c) {                          // 2 waves dump their quadrants
            #pragma unroll
            for (int nt = 0; nt < 4; ++nt) {
                int lcol = wn * 64 + nt * 16 + lr;
                #pragma unroll
                for (int mt = 0; mt < 4; ++mt) {
                    int lrow = mt * 16 + lg * 4;
                    scl[(lrow + 0) * 132 + lcol] = acc[mt][nt][0];
                    scl[(lrow + 1) * 132 + lcol] = acc[mt][nt][1];
                    scl[(lrow + 2) * 132 + lcol] = acc[mt][nt][2];
                    scl[(lrow + 3) * 132 + lcol] = acc[mt][nt][3];
                }
            }
        }
        __syncthreads();
        unsigned wv = mb[col * 4 + c * 2 + qt];
        #pragma unroll
        for (int i = 0; i < 32; ++i) {
            int lrow = qt * 32 + i;
            float sc = scl[lrow * 132 + col];
            sc = ((wv >> i) & 1u) ? sc : 0.0f;
            ins10(s10, i10, sc, a0g + c * 64 + lrow);
        }
    }

    __syncthreads();                            // scl dead; reuse for merge
    #pragma unroll
    for (int k = 0; k < 10; ++k) {
        ms[col * 20 + qt * 10 + k] = s10[k];
        mi[col * 20 + qt * 10 + k] = i10[k];
    }
    __syncthreads();
    if (t < 128) {
        float fs[10]; int fi[10];
        #pragma unroll
        for (int q = 0; q < 10; ++q) { fs[q] = -INFINITY; fi[q] = 0x7fffffff; }
        for (int j = 0; j < 20; ++j)
            ins10(fs, fi, ms[t * 20 + j], mi[t * 20 + j]);
        size_t base = ((size_t)(b0 + t) * NT128 + gt) * 10;
        #pragma unroll
        for (int k = 0; k < 10; ++k) { cs[base + k] = fs[k]; ci[base + k] = fi[k]; }
    }
}

// ---------------------------------------------------------------------------
// merge_rescore2: stream 10000 cands -> per-thread top-16 (regs) -> LDS 4096
// -> global top-16 -> fp64 rescore -> final top-10 + gather.
// ---------------------------------------------------------------------------
__global__ __launch_bounds__(256) void merge_rescore2_k(
    const float* __restrict__ cs, const int* __restrict__ ci,
    const float* __restrict__ P, const float* __restrict__ ANS,
    const double* __restrict__ invn64, const float* __restrict__ mask,
    float* __restrict__ out)
{
    __shared__ float  ls[4096];
    __shared__ int    li[4096];
    __shared__ float  rrs[4];
    __shared__ int    rri[4], rrp[4];
    __shared__ int    topi_s[16];
    __shared__ double tops_s[16];
    __shared__ int    fin_s[10];
    int row = blockIdx.x, tid = threadIdx.x;

    float s16[16]; int i16[16];
    #pragma unroll
    for (int q = 0; q < 16; ++q) { s16[q] = -INFINITY; i16[q] = 0x7fffffff; }
    const float* csr = cs + (size_t)row * CAND2;
    const int*   cir = ci + (size_t)row * CAND2;
    for (int j = tid; j < CAND2; j += 256)
        ins16(s16, i16, csr[j], cir[j]);
    #pragma unroll
    for (int q = 0; q < 16; ++q) { ls[tid * 16 + q] = s16[q]; li[tid * 16 + q] = i16[q]; }
    __syncthreads();

    for (int it = 0; it < 16; ++it) {
        float bsv = -INFINITY; int bi = 0x7fffffff, bp = -1;
        for (int j = tid; j < 4096; j += 256) {
            float s = ls[j];
            if (s > bsv || (s == bsv && li[j] < bi)) { bsv = s; bi = li[j]; bp = j; }
        }
        #pragma unroll
        for (int o = 32; o; o >>= 1) {
            float os = __shfl_down(bsv, o);
            int oi = __shfl_down(bi, o);
            int op = __shfl_down(bp, o);
            if (os > bsv || (os == bsv && oi < bi)) { bsv = os; bi = oi; bp = op; }
        }
        if ((tid & 63) == 0) { int w = tid >> 6; rrs[w] = bsv; rri[w] = bi; rrp[w] = bp; }
        __syncthreads();
        if (tid == 0) {
            for (int w = 1; w < 4; ++w)
                if (rrs[w] > bsv || (rrs[w] == bsv && rri[w] < bi)) {
                    bsv = rrs[w]; bi = rri[w]; bp = rrp[w];
                }
            topi_s[it] = bi;
            ls[bp] = -INFINITY;
        }
        __syncthreads();
    }

    // fp64 rescore: 16 threads per candidate
    int c = tid >> 4, part = tid & 15;
    int aidx = topi_s[c];
    const float4* p4 = (const float4*)(P + (size_t)row * DIM);
    const float4* a4 = (const float4*)(ANS + (size_t)aidx * DIM);
    double sum = 0.0;
    #pragma unroll
    for (int i = 0; i < 12; ++i) {
        float4 pv = p4[part * 12 + i];
        float4 av = a4[part * 12 + i];
        sum += (double)pv.x * av.x + (double)pv.y * av.y
             + (double)pv.z * av.z + (double)pv.w * av.w;
    }
    #pragma unroll
    for (int o = 8; o; o >>= 1) sum += __shfl_down(sum, o, 16);
    if (part == 0) {
        float m = mask[(size_t)row * NANS + aidx];
        tops_s[c] = sum * invn64[aidx] * (double)m;
    }
    __syncthreads();

    if (tid == 0) {
        unsigned used = 0;
        for (int k = 0; k < 10; ++k) {
            int bj = -1;
            for (int j = 0; j < 16; ++j) {
                if (used & (1u << j)) continue;
                if (bj < 0 || tops_s[j] > tops_s[bj] ||
                    (tops_s[j] == tops_s[bj] && topi_s[j] < topi_s[bj])) bj = j;
            }
            used |= 1u << bj;
            out[(size_t)row * 10 + k] = (float)tops_s[bj];
            out[10240 + (size_t)row * 10 + k] = (float)topi_s[bj];
            fin_s[k] = topi_s[bj];
        }
    }
    __syncthreads();

    for (int k = 0; k < 10; ++k) {
        int id = fin_s[k];
        const float* arow = ANS + (size_t)id * DIM;
        float* orow = out + 20480 + ((size_t)(row * 10 + k)) * DIM;
        for (int d = tid; d < DIM; d += 256) orow[d] = arow[d];
    }
}

// ---------------------------------------------------------------------------
extern "C" void kernel_launch(void* const* d_in, const int* in_sizes, int n_in,
                              void* d_out, int out_size, void* d_ws, size_t ws_size,
                              hipStream_t stream)
{
    (void)in_sizes; (void)n_in; (void)out_size;
    const float* visual = (const float*)d_in[0];
    const float* mask   = (const float*)d_in[2];
    const float* ans    = (const float*)d_in[3];
    const float* wv = (const float*)d_in[8];
    const float* bv = (const float*)d_in[9];
    const float* wo = (const float*)d_in[10];
    const float* bo = (const float*)d_in[11];
    const float* fw = (const float*)d_in[12];
    const float* fb = (const float*)d_in[13];
    const float* lg = (const float*)d_in[14];
    const float* lb = (const float*)d_in[15];
    const float* sw = (const float*)d_in[16];
    const float* sb = (const float*)d_in[17];
    float* out = (float*)d_out;

    // ---- workspace: persistent first, transient upstream + AB share tail ----
    char* w = (char*)d_ws;
    float*    P        = (float*)w;    w += (size_t)BATCH * DIM * 4;        // 3.1 MB
    short*    Pb       = (short*)w;    w += (size_t)BATCH * DIM * 2;        // 1.6 MB
    double*   invn64   = (double*)w;   w += (size_t)NANS * 8;               // 1.0 MB
    float*    cs       = (float*)w;    w += (size_t)BATCH * CAND2 * 4;      // 41 MB
    int*      ci       = (int*)w;      w += (size_t)BATCH * CAND2 * 4;      // 41 MB
    unsigned* bits     = (unsigned*)w; w += (size_t)BATCH * NWORDS * 4;     // 16.4 MB
    char*     tail     = w;
    float*    fused_in = (float*)tail;
    float*    v        = fused_in + (size_t)BATCH * 1536;
    float*    h        = v + (size_t)BATCH * DIM;
    short*    AB       = (short*)tail; // aliases upstream transients after death

    size_t used = (size_t)(tail - (char*)d_ws);
    size_t atile_bytes = (size_t)256 * DIM * 2;                // 393216 (256-row units)
    size_t avail = (ws_size > used) ? (ws_size - used) : atile_bytes;
    int CA = (int)(avail / atile_bytes);
    if (CA < 1) CA = 1;
    if (CA > 500) CA = 500;
    int nch = (500 + CA - 1) / CA;

    copy_visual_k<<<512, 256, 0, stream>>>(visual, fused_in);
    gemm_bias_k<<<dim3(16, 12), 256, 0, stream>>>(visual, DIM, wv, bv, v, DIM, DIM);
    gemm_bias_k<<<dim3(16, 12), 256, 0, stream>>>(v, DIM, wo, bo, fused_in + DIM, 1536, DIM);
    gemm_bias_k<<<dim3(16, 12), 256, 0, stream>>>(fused_in, 1536, fw, fb, h, DIM, 1536);
    ln_gelu_k<<<BATCH, 256, 0, stream>>>(h, lg, lb);
    gemm_bias_k<<<dim3(16, 12), 256, 0, stream>>>(h, DIM, sw, sb, P, DIM, DIM);
    l2norm_bf_k<<<BATCH, 256, 0, stream>>>(P, Pb);
    prep_mask_k<<<BATCH, 256, 0, stream>>>(mask, bits);
    // ---- upstream transients dead from here; AB may reuse them ----

    for (int ch = 0; ch < nch; ++ch) {
        int atile0 = ch * CA;
        int catiles = 500 - atile0; if (catiles > CA) catiles = CA;
        int nrows = catiles * 256;
        int nt128 = catiles * 2;
        prep_ans_k<<<(nrows + 3) / 4, 256, 0, stream>>>(ans, atile0 * 256, nrows,
                                                        invn64, AB);
        big4_k<<<nt128 * 8, 256, 0, stream>>>(Pb, AB, bits, cs, ci,
                                              atile0 * 2, nt128);
    }

    merge_rescore2_k<<<BATCH, 256, 0, stream>>>(cs, ci, P, ans, invn64, mask, out);
}

// Round 8
// 2759.592 us; speedup vs baseline: 1.5602x; 1.4965x over previous
//
#include <hip/hip_runtime.h>
#include <math.h>

#define DIM    768
#define BATCH  1024
#define NANS   128000
#define NT128  1000             // 128-answer shortlist tiles
#define CAND2  (NT128*10)       // 10000 shortlist candidates per row
#define NWORDS 4000             // mask bit-words per batch row (128000/32)

typedef short  bf16x8 __attribute__((ext_vector_type(8)));
typedef float  f32x4  __attribute__((ext_vector_type(4)));

__device__ __forceinline__ short f2bf(float x)
{
    unsigned u = __builtin_bit_cast(unsigned, x);
    u += 0x7fffu + ((u >> 16) & 1u);          // RNE (no NaN inputs here)
    return (short)(u >> 16);
}

__device__ __forceinline__ void gload16(const void* g, void* l)
{
    __builtin_amdgcn_global_load_lds(
        (const __attribute__((address_space(1))) void*)g,
        (__attribute__((address_space(3))) void*)l, 16, 0, 0);
}

// sorted-descending top-10 insertion (static indices only)
__device__ __forceinline__ void ins10(float (&s)[10], int (&ix)[10], float v, int vi)
{
    if (v > s[9] || (v == s[9] && vi < ix[9])) {
        s[9] = v; ix[9] = vi;
        #pragma unroll
        for (int q = 9; q > 0; --q) {
            bool sw = (s[q] > s[q-1]) || (s[q] == s[q-1] && ix[q] < ix[q-1]);
            float ts = s[q-1]; int ti = ix[q-1];
            s[q-1] = sw ? s[q] : s[q-1]; ix[q-1] = sw ? ix[q] : ix[q-1];
            s[q]   = sw ? ts   : s[q];   ix[q]   = sw ? ti   : ix[q];
        }
    }
}

__device__ __forceinline__ void ins16(float (&s)[16], int (&ix)[16], float v, int vi)
{
    if (v > s[15] || (v == s[15] && vi < ix[15])) {
        s[15] = v; ix[15] = vi;
        #pragma unroll
        for (int q = 15; q > 0; --q) {
            bool sw = (s[q] > s[q-1]) || (s[q] == s[q-1] && ix[q] < ix[q-1]);
            float ts = s[q-1]; int ti = ix[q-1];
            s[q-1] = sw ? s[q] : s[q-1]; ix[q-1] = sw ? ix[q] : ix[q-1];
            s[q]   = sw ? ts   : s[q];   ix[q]   = sw ? ti   : ix[q];
        }
    }
}

// ---------------------------------------------------------------------------
// Upstream GEMM: C[M,N] = A[M,K] @ W[N,K]^T + bias   (fp32)
// ---------------------------------------------------------------------------
__global__ __launch_bounds__(256, 2) void gemm_bias_k(
    const float* __restrict__ A, int lda,
    const float* __restrict__ W,
    const float* __restrict__ bias,
    float* __restrict__ C, int ldc, int K)
{
    __shared__ float as[32][68];
    __shared__ float bs[32][68];
    int m0 = blockIdx.x * 64, n0 = blockIdx.y * 64;
    int tid = threadIdx.x;
    int tm = tid & 15, tn = tid >> 4;
    int sr = tid >> 3, skq = tid & 7;
    float acc[4][4] = {};
    for (int k0 = 0; k0 < K; k0 += 32) {
        __syncthreads();
        #pragma unroll
        for (int p = 0; p < 2; ++p) {
            int r = sr + 32 * p;
            float4 av = *(const float4*)&A[(size_t)(m0 + r) * lda + k0 + skq * 4];
            as[skq*4+0][r] = av.x; as[skq*4+1][r] = av.y;
            as[skq*4+2][r] = av.z; as[skq*4+3][r] = av.w;
            float4 wv = *(const float4*)&W[(size_t)(n0 + r) * K + k0 + skq * 4];
            bs[skq*4+0][r] = wv.x; bs[skq*4+1][r] = wv.y;
            bs[skq*4+2][r] = wv.z; bs[skq*4+3][r] = wv.w;
        }
        __syncthreads();
        #pragma unroll 8
        for (int k = 0; k < 32; ++k) {
            float a4[4], b4[4];
            *(float4*)a4 = *(const float4*)&as[k][tm*4];
            *(float4*)b4 = *(const float4*)&bs[k][tn*4];
            #pragma unroll
            for (int i = 0; i < 4; ++i)
                #pragma unroll
                for (int j = 0; j < 4; ++j)
                    acc[i][j] = fmaf(a4[i], b4[j], acc[i][j]);
        }
    }
    float4 bv4 = *(const float4*)&bias[n0 + tn*4];
    #pragma unroll
    for (int i = 0; i < 4; ++i) {
        float4 c4;
        c4.x = acc[i][0] + bv4.x; c4.y = acc[i][1] + bv4.y;
        c4.z = acc[i][2] + bv4.z; c4.w = acc[i][3] + bv4.w;
        *(float4*)&C[(size_t)(m0 + tm*4 + i) * ldc + n0 + tn*4] = c4;
    }
}

// ---------------------------------------------------------------------------
__global__ void copy_visual_k(const float* __restrict__ src, float* __restrict__ dst)
{
    int idx = blockIdx.x * 256 + threadIdx.x;          // float4 index
    const int total = BATCH * (DIM / 4);
    for (; idx < total; idx += 512 * 256) {
        int b = idx / (DIM / 4), c = idx % (DIM / 4);
        ((float4*)dst)[(size_t)b * (1536 / 4) + c] = ((const float4*)src)[idx];
    }
}

// ---------------------------------------------------------------------------
__device__ __forceinline__ float block_sum(float v, float* red)
{
    #pragma unroll
    for (int o = 32; o; o >>= 1) v += __shfl_down(v, o);
    if ((threadIdx.x & 63) == 0) red[threadIdx.x >> 6] = v;
    __syncthreads();
    float r = red[0] + red[1] + red[2] + red[3];
    __syncthreads();
    return r;
}

__global__ __launch_bounds__(256) void ln_gelu_k(float* __restrict__ H,
        const float* __restrict__ g, const float* __restrict__ b)
{
    __shared__ float red[4];
    int row = blockIdx.x, tid = threadIdx.x;
    float* hr = H + (size_t)row * DIM;
    float v0 = hr[tid], v1 = hr[tid + 256], v2 = hr[tid + 512];
    float mu = block_sum(v0 + v1 + v2, red) * (1.0f / 768.0f);
    float d0 = v0 - mu, d1 = v1 - mu, d2 = v2 - mu;
    float var = block_sum(d0*d0 + d1*d1 + d2*d2, red) * (1.0f / 768.0f);
    float rinv = 1.0f / sqrtf(var + 1e-5f);
    #pragma unroll
    for (int q = 0; q < 3; ++q) {
        int d = tid + 256 * q;
        float dd = (q == 0 ? d0 : (q == 1 ? d1 : d2));
        float y = dd * rinv * g[d] + b[d];
        hr[d] = 0.5f * y * (1.0f + erff(y * 0.70710678118654752f));
    }
}

// l2-normalize P in place, also emit bf16 copy
__global__ __launch_bounds__(256) void l2norm_bf_k(float* __restrict__ P,
        short* __restrict__ Pb)
{
    __shared__ float red[4];
    int row = blockIdx.x, tid = threadIdx.x;
    float* pr = P + (size_t)row * DIM;
    short* pb = Pb + (size_t)row * DIM;
    float v0 = pr[tid], v1 = pr[tid + 256], v2 = pr[tid + 512];
    float ss = block_sum(v0*v0 + v1*v1 + v2*v2, red);
    float inv = 1.0f / fmaxf(sqrtf(ss), 1e-12f);
    v0 *= inv; v1 *= inv; v2 *= inv;
    pr[tid] = v0; pr[tid + 256] = v1; pr[tid + 512] = v2;
    pb[tid] = f2bf(v0); pb[tid + 256] = f2bf(v1); pb[tid + 512] = f2bf(v2);
}

// ---------------------------------------------------------------------------
// prep_ans: fp64 row norm -> inv64[row]; unit-normalized bf16 rows into AB.
// ---------------------------------------------------------------------------
__global__ __launch_bounds__(256) void prep_ans_k(
    const float* __restrict__ ANS, int row0, int nrows,
    double* __restrict__ inv64, short* __restrict__ AB)
{
    int r = blockIdx.x * 4 + (threadIdx.x >> 6);
    if (r >= nrows) return;
    int row = row0 + r;
    int lane = threadIdx.x & 63;
    const float4* a4 = (const float4*)(ANS + (size_t)row * DIM);
    float4 x0 = a4[lane], x1 = a4[lane + 64], x2 = a4[lane + 128];
    double ss = (double)x0.x*x0.x + (double)x0.y*x0.y + (double)x0.z*x0.z + (double)x0.w*x0.w
              + (double)x1.x*x1.x + (double)x1.y*x1.y + (double)x1.z*x1.z + (double)x1.w*x1.w
              + (double)x2.x*x2.x + (double)x2.y*x2.y + (double)x2.z*x2.z + (double)x2.w*x2.w;
    #pragma unroll
    for (int o = 32; o; o >>= 1) ss += __shfl_xor(ss, o);
    double inv = 1.0 / fmax(sqrt(ss), 1e-12);
    if (lane == 0) inv64[row] = inv;
    float invf = (float)inv;
    short* ob = AB + (size_t)r * DIM;
    ushort4 o0, o1, o2;
    o0.x = (unsigned short)f2bf(x0.x*invf); o0.y = (unsigned short)f2bf(x0.y*invf);
    o0.z = (unsigned short)f2bf(x0.z*invf); o0.w = (unsigned short)f2bf(x0.w*invf);
    o1.x = (unsigned short)f2bf(x1.x*invf); o1.y = (unsigned short)f2bf(x1.y*invf);
    o1.z = (unsigned short)f2bf(x1.z*invf); o1.w = (unsigned short)f2bf(x1.w*invf);
    o2.x = (unsigned short)f2bf(x2.x*invf); o2.y = (unsigned short)f2bf(x2.y*invf);
    o2.z = (unsigned short)f2bf(x2.z*invf); o2.w = (unsigned short)f2bf(x2.w*invf);
    *(ushort4*)&ob[lane * 4]           = o0;
    *(ushort4*)&ob[(lane + 64) * 4]    = o1;
    *(ushort4*)&ob[(lane + 128) * 4]   = o2;
}

// ---------------------------------------------------------------------------
// prep_mask: float mask [1024][128000] -> bits [1024][4000]
// ---------------------------------------------------------------------------
__global__ __launch_bounds__(256) void prep_mask_k(
    const float* __restrict__ mask, unsigned* __restrict__ bits)
{
    int row = blockIdx.x;
    const float* mr = mask + (size_t)row * NANS;
    unsigned* br = bits + (size_t)row * NWORDS;
    for (int w = threadIdx.x; w < NWORDS; w += 256) {
        const float4* p = (const float4*)(mr + w * 32);
        unsigned b = 0;
        #pragma unroll
        for (int q = 0; q < 8; ++q) {
            float4 v = p[q];
            b |= ((unsigned)(v.x != 0.f)) << (q*4+0);
            b |= ((unsigned)(v.y != 0.f)) << (q*4+1);
            b |= ((unsigned)(v.z != 0.f)) << (q*4+2);
            b |= ((unsigned)(v.w != 0.f)) << (q*4+3);
        }
        br[w] = b;
    }
}

// ---------------------------------------------------------------------------
// big4_k: m97-structure MFMA GEMM + shortlist.
// 256 threads / 4 waves; tile 128 answers x 128 batch; BK=32; 24 K-steps;
// global_load_lds(16) staging into linear LDS [row][32]; 2 barriers/K-step.
// __launch_bounds__(256,2): 2nd arg = min BLOCKS/CU (CUDA semantics, verified
// R5/R6/R7: (512,4)->cap64 spill, (512,2)->cap128 ok, none->cap128 spill).
// (256,2) -> 2 waves/SIMD min -> 256-reg cap; demand ~150 fits, no spill.
// ---------------------------------------------------------------------------
__global__ __launch_bounds__(256, 2) void big4_k(
    const short* __restrict__ Pb,       // [1024][768] unit-norm bf16
    const short* __restrict__ AB,       // chunk rows, unit-norm bf16
    const unsigned* __restrict__ bits,  // [1024][4000]
    float* __restrict__ cs, int* __restrict__ ci,
    int t128_0, int nt128)
{
    __shared__ __align__(16) char smem[35840];
    short* a_sh = (short*)smem;                 // [128][32] = 8192 B
    short* b_sh = (short*)(smem + 8192);        // [128][32] = 8192 B
    unsigned* mb = (unsigned*)(smem + 33792);   // [128][4]  = 2048 B
    float* scl = (float*)smem;                  // reuse: [64][132] = 33792 B
    float* ms  = (float*)smem;                  // reuse: [128][20]
    int*   mi  = (int*)(smem + 10240);          // reuse: [128][20]

    // XCD swizzle: blocks on one XCD share answer tiles (nwg % 8 == 0)
    int bid = blockIdx.x;
    int v = (bid & 7) * nt128 + (bid >> 3);
    int at = v >> 3, bt = v & 7;
    int gt = t128_0 + at;                       // global 128-tile id
    int a0l = at * 128, a0g = gt * 128, b0 = bt * 128;

    int t = threadIdx.x;
    int lane = t & 63, wid = t >> 6;
    int wm = wid & 1, wn = wid >> 1;            // 2x2 wave grid of 64x64
    int lr = lane & 15, lg = lane >> 4;

    // stage mask bits: 128 rows x 4 words
    mb[t]       = bits[(size_t)(b0 + (t >> 2)) * NWORDS + gt * 4 + (t & 3)];
    mb[t + 256] = bits[(size_t)(b0 + 64 + (t >> 2)) * NWORDS + gt * 4 + (t & 3)];

    // staging addresses: chunk c of 16 B; row = c>>2, seg = c&3; thread owns
    // chunks t (rows 0-63) and t+256 (rows 64-127) for both A and B.
    const char* gA0 = (const char*)(AB + (size_t)(a0l + (t >> 2)) * DIM + (t & 3) * 8);
    const char* gA1 = (const char*)(AB + (size_t)(a0l + 64 + (t >> 2)) * DIM + (t & 3) * 8);
    const char* gB0 = (const char*)(Pb + (size_t)(b0 + (t >> 2)) * DIM + (t & 3) * 8);
    const char* gB1 = (const char*)(Pb + (size_t)(b0 + 64 + (t >> 2)) * DIM + (t & 3) * 8);
    char* la0 = (char*)a_sh + t * 16;
    char* la1 = (char*)a_sh + 4096 + t * 16;
    char* lb0 = (char*)b_sh + t * 16;
    char* lb1 = (char*)b_sh + 4096 + t * 16;

    f32x4 acc[4][4];
    #pragma unroll
    for (int i = 0; i < 4; ++i)
        #pragma unroll
        for (int j = 0; j < 4; ++j)
            acc[i][j] = (f32x4){0.f, 0.f, 0.f, 0.f};

    for (int kt = 0; kt < 24; ++kt) {
        int kb = kt * 64;                       // byte offset in a 768-short row
        gload16(gA0 + kb, la0);
        gload16(gA1 + kb, la1);
        gload16(gB0 + kb, lb0);
        gload16(gB1 + kb, lb1);
        __syncthreads();                        // drain vmcnt + barrier
        bf16x8 af[4], bg[4];
        #pragma unroll
        for (int mt = 0; mt < 4; ++mt)
            af[mt] = *(const bf16x8*)(a_sh + (wm*64 + mt*16 + lr) * 32 + lg*8);
        #pragma unroll
        for (int nt = 0; nt < 4; ++nt)
            bg[nt] = *(const bf16x8*)(b_sh + (wn*64 + nt*16 + lr) * 32 + lg*8);
        #pragma unroll
        for (int mt = 0; mt < 4; ++mt)
            #pragma unroll
            for (int nt = 0; nt < 4; ++nt)
                acc[mt][nt] = __builtin_amdgcn_mfma_f32_16x16x32_bf16(
                    af[mt], bg[nt], acc[mt][nt], 0, 0, 0);
        __syncthreads();                        // reads done before next stage
    }

    // ---- epilogue: bitmask + per-column top-10 over 128 answers ----
    float s10[10]; int i10[10];
    #pragma unroll
    for (int q = 0; q < 10; ++q) { s10[q] = -INFINITY; i10[q] = 0x7fffffff; }
    int col = t & 127, qt = t >> 7;             // qt 0..1: 32 answers each

    for (int c = 0; c < 2; ++c) {               // 64-answer chunks
        __syncthreads();
        if (wm == c) {                          // 2 waves dump their quadrants
            #pragma unroll
            for (int nt = 0; nt < 4; ++nt) {
                int lcol = wn * 64 + nt * 16 + lr;
                #pragma unroll
                for (int mt = 0; mt < 4; ++mt) {
                    int lrow = mt * 16 + lg * 4;
                    scl[(lrow + 0) * 132 + lcol] = acc[mt][nt][0];
                    scl[(lrow + 1) * 132 + lcol] = acc[mt][nt][1];
                    scl[(lrow + 2) * 132 + lcol] = acc[mt][nt][2];
                    scl[(lrow + 3) * 132 + lcol] = acc[mt][nt][3];
                }
            }
        }
        __syncthreads();
        unsigned wv = mb[col * 4 + c * 2 + qt];
        #pragma unroll
        for (int i = 0; i < 32; ++i) {
            int lrow = qt * 32 + i;
            float sc = scl[lrow * 132 + col];
            sc = ((wv >> i) & 1u) ? sc : 0.0f;
            ins10(s10, i10, sc, a0g + c * 64 + lrow);
        }
    }

    __syncthreads();                            // scl dead; reuse for merge
    #pragma unroll
    for (int k = 0; k < 10; ++k) {
        ms[col * 20 + qt * 10 + k] = s10[k];
        mi[col * 20 + qt * 10 + k] = i10[k];
    }
    __syncthreads();
    if (t < 128) {
        float fs[10]; int fi[10];
        #pragma unroll
        for (int q = 0; q < 10; ++q) { fs[q] = -INFINITY; fi[q] = 0x7fffffff; }
        for (int j = 0; j < 20; ++j)
            ins10(fs, fi, ms[t * 20 + j], mi[t * 20 + j]);
        size_t base = ((size_t)(b0 + t) * NT128 + gt) * 10;
        #pragma unroll
        for (int k = 0; k < 10; ++k) { cs[base + k] = fs[k]; ci[base + k] = fi[k]; }
    }
}

// ---------------------------------------------------------------------------
// merge_rescore2: stream 10000 cands -> per-thread top-16 (regs) -> LDS 4096
// -> global top-16 -> fp64 rescore -> final top-10 + gather.
// ---------------------------------------------------------------------------
__global__ __launch_bounds__(256) void merge_rescore2_k(
    const float* __restrict__ cs, const int* __restrict__ ci,
    const float* __restrict__ P, const float* __restrict__ ANS,
    const double* __restrict__ invn64, const float* __restrict__ mask,
    float* __restrict__ out)
{
    __shared__ float  ls[4096];
    __shared__ int    li[4096];
    __shared__ float  rrs[4];
    __shared__ int    rri[4], rrp[4];
    __shared__ int    topi_s[16];
    __shared__ double tops_s[16];
    __shared__ int    fin_s[10];
    int row = blockIdx.x, tid = threadIdx.x;

    float s16[16]; int i16[16];
    #pragma unroll
    for (int q = 0; q < 16; ++q) { s16[q] = -INFINITY; i16[q] = 0x7fffffff; }
    const float* csr = cs + (size_t)row * CAND2;
    const int*   cir = ci + (size_t)row * CAND2;
    for (int j = tid; j < CAND2; j += 256)
        ins16(s16, i16, csr[j], cir[j]);
    #pragma unroll
    for (int q = 0; q < 16; ++q) { ls[tid * 16 + q] = s16[q]; li[tid * 16 + q] = i16[q]; }
    __syncthreads();

    for (int it = 0; it < 16; ++it) {
        float bsv = -INFINITY; int bi = 0x7fffffff, bp = -1;
        for (int j = tid; j < 4096; j += 256) {
            float s = ls[j];
            if (s > bsv || (s == bsv && li[j] < bi)) { bsv = s; bi = li[j]; bp = j; }
        }
        #pragma unroll
        for (int o = 32; o; o >>= 1) {
            float os = __shfl_down(bsv, o);
            int oi = __shfl_down(bi, o);
            int op = __shfl_down(bp, o);
            if (os > bsv || (os == bsv && oi < bi)) { bsv = os; bi = oi; bp = op; }
        }
        if ((tid & 63) == 0) { int w = tid >> 6; rrs[w] = bsv; rri[w] = bi; rrp[w] = bp; }
        __syncthreads();
        if (tid == 0) {
            for (int w = 1; w < 4; ++w)
                if (rrs[w] > bsv || (rrs[w] == bsv && rri[w] < bi)) {
                    bsv = rrs[w]; bi = rri[w]; bp = rrp[w];
                }
            topi_s[it] = bi;
            ls[bp] = -INFINITY;
        }
        __syncthreads();
    }

    // fp64 rescore: 16 threads per candidate
    int c = tid >> 4, part = tid & 15;
    int aidx = topi_s[c];
    const float4* p4 = (const float4*)(P + (size_t)row * DIM);
    const float4* a4 = (const float4*)(ANS + (size_t)aidx * DIM);
    double sum = 0.0;
    #pragma unroll
    for (int i = 0; i < 12; ++i) {
        float4 pv = p4[part * 12 + i];
        float4 av = a4[part * 12 + i];
        sum += (double)pv.x * av.x + (double)pv.y * av.y
             + (double)pv.z * av.z + (double)pv.w * av.w;
    }
    #pragma unroll
    for (int o = 8; o; o >>= 1) sum += __shfl_down(sum, o, 16);
    if (part == 0) {
        float m = mask[(size_t)row * NANS + aidx];
        tops_s[c] = sum * invn64[aidx] * (double)m;
    }
    __syncthreads();

    if (tid == 0) {
        unsigned used = 0;
        for (int k = 0; k < 10; ++k) {
            int bj = -1;
            for (int j = 0; j < 16; ++j) {
                if (used & (1u << j)) continue;
                if (bj < 0 || tops_s[j] > tops_s[bj] ||
                    (tops_s[j] == tops_s[bj] && topi_s[j] < topi_s[bj])) bj = j;
            }
            used |= 1u << bj;
            out[(size_t)row * 10 + k] = (float)tops_s[bj];
            out[10240 + (size_t)row * 10 + k] = (float)topi_s[bj];
            fin_s[k] = topi_s[bj];
        }
    }
    __syncthreads();

    for (int k = 0; k < 10; ++k) {
        int id = fin_s[k];
        const float* arow = ANS + (size_t)id * DIM;
        float* orow = out + 20480 + ((size_t)(row * 10 + k)) * DIM;
        for (int d = tid; d < DIM; d += 256) orow[d] = arow[d];
    }
}

// ---------------------------------------------------------------------------
extern "C" void kernel_launch(void* const* d_in, const int* in_sizes, int n_in,
                              void* d_out, int out_size, void* d_ws, size_t ws_size,
                              hipStream_t stream)
{
    (void)in_sizes; (void)n_in; (void)out_size;
    const float* visual = (const float*)d_in[0];
    const float* mask   = (const float*)d_in[2];
    const float* ans    = (const float*)d_in[3];
    const float* wv = (const float*)d_in[8];
    const float* bv = (const float*)d_in[9];
    const float* wo = (const float*)d_in[10];
    const float* bo = (const float*)d_in[11];
    const float* fw = (const float*)d_in[12];
    const float* fb = (const float*)d_in[13];
    const float* lg = (const float*)d_in[14];
    const float* lb = (const float*)d_in[15];
    const float* sw = (const float*)d_in[16];
    const float* sb = (const float*)d_in[17];
    float* out = (float*)d_out;

    // ---- workspace: persistent first, transient upstream + AB share tail ----
    char* w = (char*)d_ws;
    float*    P        = (float*)w;    w += (size_t)BATCH * DIM * 4;        // 3.1 MB
    short*    Pb       = (short*)w;    w += (size_t)BATCH * DIM * 2;        // 1.6 MB
    double*   invn64   = (double*)w;   w += (size_t)NANS * 8;               // 1.0 MB
    float*    cs       = (float*)w;    w += (size_t)BATCH * CAND2 * 4;      // 41 MB
    int*      ci       = (int*)w;      w += (size_t)BATCH * CAND2 * 4;      // 41 MB
    unsigned* bits     = (unsigned*)w; w += (size_t)BATCH * NWORDS * 4;     // 16.4 MB
    char*     tail     = w;
    float*    fused_in = (float*)tail;
    float*    v        = fused_in + (size_t)BATCH * 1536;
    float*    h        = v + (size_t)BATCH * DIM;
    short*    AB       = (short*)tail; // aliases upstream transients after death

    size_t used = (size_t)(tail - (char*)d_ws);
    size_t atile_bytes = (size_t)256 * DIM * 2;                // 393216 (256-row units)
    size_t avail = (ws_size > used) ? (ws_size - used) : atile_bytes;
    int CA = (int)(avail / atile_bytes);
    if (CA < 1) CA = 1;
    if (CA > 500) CA = 500;
    int nch = (500 + CA - 1) / CA;

    copy_visual_k<<<512, 256, 0, stream>>>(visual, fused_in);
    gemm_bias_k<<<dim3(16, 12), 256, 0, stream>>>(visual, DIM, wv, bv, v, DIM, DIM);
    gemm_bias_k<<<dim3(16, 12), 256, 0, stream>>>(v, DIM, wo, bo, fused_in + DIM, 1536, DIM);
    gemm_bias_k<<<dim3(16, 12), 256, 0, stream>>>(fused_in, 1536, fw, fb, h, DIM, 1536);
    ln_gelu_k<<<BATCH, 256, 0, stream>>>(h, lg, lb);
    gemm_bias_k<<<dim3(16, 12), 256, 0, stream>>>(h, DIM, sw, sb, P, DIM, DIM);
    l2norm_bf_k<<<BATCH, 256, 0, stream>>>(P, Pb);
    prep_mask_k<<<BATCH, 256, 0, stream>>>(mask, bits);
    // ---- upstream transients dead from here; AB may reuse them ----

    for (int ch = 0; ch < nch; ++ch) {
        int atile0 = ch * CA;
        int catiles = 500 - atile0; if (catiles > CA) catiles = CA;
        int nrows = catiles * 256;
        int nt128 = catiles * 2;
        prep_ans_k<<<(nrows + 3) / 4, 256, 0, stream>>>(ans, atile0 * 256, nrows,
                                                        invn64, AB);
        big4_k<<<nt128 * 8, 256, 0, stream>>>(Pb, AB, bits, cs, ci,
                                              atile0 * 2, nt128);
    }

    merge_rescore2_k<<<BATCH, 256, 0, stream>>>(cs, ci, P, ans, invn64, mask, out);
}